// Round 1
// baseline (703.014 us; speedup 1.0000x reference)
//
#include <hip/hip_runtime.h>
#include <math.h>
#include <type_traits>

#define DMODEL 1024
#define NSEQ   4096
#define MTOT   16384

typedef unsigned short ushortT;
typedef __attribute__((ext_vector_type(8))) short short8;
typedef __attribute__((ext_vector_type(4))) float f32x4;

__device__ __forceinline__ float gelu_f(float x) {
    return 0.5f * x * (1.0f + erff(x * 0.70710678118654752440f));
}
__device__ __forceinline__ double gelu_d(double x) {
    return 0.5 * x * (1.0 + erf(x * 0.70710678118654752440));
}
__device__ __forceinline__ ushortT f2bf(float f) {
    unsigned u = __float_as_uint(f);
    u += 0x7FFFu + ((u >> 16) & 1u);   // round-to-nearest-even
    return (ushortT)(u >> 16);
}
__device__ __forceinline__ float bf2f(ushortT b) {
    return __uint_as_float(((unsigned)b) << 16);
}
// async global->LDS, 16B per lane; LDS dest = wave-uniform base + lane*16
__device__ __forceinline__ void gload16(const void* g, void* l) {
    __builtin_amdgcn_global_load_lds(
        (const __attribute__((address_space(1))) unsigned*)g,
        (__attribute__((address_space(3))) unsigned*)l, 16, 0, 0);
}

// ---------------- bf16 MFMA GEMM (m97 structure) ----------------
// C = epi(A @ Bt^T [+bias]); A [M,K] bf16 row-major (lda), Bt [N,K] bf16 (ldb).
// EPI_GELU_ADDQ_BF16: C = gelu(acc + bias[col] + Q[gidx[row]][col])  (gather-add epilogue)
enum { EPI_BF16 = 0, EPI_GELU_BIAS_BF16 = 1, EPI_BIAS_F32 = 2, EPI_TRANS_BF16 = 3,
       EPI_GELU_ADDQ_BF16 = 4 };

template<int EPI>
__global__ __launch_bounds__(256)
void mfma_gemm(const ushortT* __restrict__ A, const ushortT* __restrict__ Bt,
               const float* __restrict__ bias, void* __restrict__ Cv,
               int K, int lda, int ldb, int ldc,
               const int* __restrict__ gidx, const ushortT* __restrict__ Qg)
{
    __shared__ ushortT As[128 * 32];
    __shared__ ushortT Bs[128 * 32];
    const int tid  = threadIdx.x;
    const int lane = tid & 63;
    const int w    = tid >> 6;
    const int wr   = (w >> 1) * 64;
    const int wc   = (w & 1) * 64;
    const int m0   = blockIdx.y * 128;
    const int n0   = blockIdx.x * 128;

    const int lrow = lane >> 2;
    const int lk   = (lane & 3) * 8;

    f32x4 acc[4][4];
    #pragma unroll
    for (int i = 0; i < 4; i++)
        #pragma unroll
        for (int j = 0; j < 4; j++) acc[i][j] = (f32x4){0.f, 0.f, 0.f, 0.f};

    for (int kk = 0; kk < K; kk += 32) {
        #pragma unroll
        for (int i = 0; i < 2; i++) {
            const ushortT* ga = A + (size_t)(m0 + w * 32 + i * 16 + lrow) * lda + kk + lk;
            gload16(ga, &As[(w * 32 + i * 16) * 32]);
            const ushortT* gb = Bt + (size_t)(n0 + w * 32 + i * 16 + lrow) * ldb + kk + lk;
            gload16(gb, &Bs[(w * 32 + i * 16) * 32]);
        }
        __syncthreads();

        const int mi = lane & 15;
        const int ko = (lane >> 4) * 8;
        short8 a[4], b[4];
        #pragma unroll
        for (int i = 0; i < 4; i++)
            a[i] = *(const short8*)&As[(wr + i * 16 + mi) * 32 + ko];
        #pragma unroll
        for (int j = 0; j < 4; j++)
            b[j] = *(const short8*)&Bs[(wc + j * 16 + mi) * 32 + ko];
        #pragma unroll
        for (int i = 0; i < 4; i++)
            #pragma unroll
            for (int j = 0; j < 4; j++)
                acc[i][j] = __builtin_amdgcn_mfma_f32_16x16x32_bf16(a[i], b[j], acc[i][j], 0, 0, 0);
        __syncthreads();
    }

    const int cr = (lane >> 4) * 4;
    const int cc = lane & 15;
    #pragma unroll
    for (int i = 0; i < 4; i++) {
        #pragma unroll
        for (int j = 0; j < 4; j++) {
            const int gr = m0 + wr + i * 16 + cr;
            const int gc = n0 + wc + j * 16 + cc;
            #pragma unroll
            for (int r = 0; r < 4; r++) {
                float v = acc[i][j][r];
                if constexpr (EPI == EPI_GELU_BIAS_BF16) v = gelu_f(v + bias[gc]);
                if constexpr (EPI == EPI_GELU_ADDQ_BF16) {
                    const int trow = gidx[gr + r];
                    v = gelu_f(v + bias[gc] + bf2f(Qg[(size_t)trow * DMODEL + gc]));
                }
                if constexpr (EPI == EPI_BIAS_F32)       v = v + bias[gc];
                if constexpr (EPI == EPI_BF16 || EPI == EPI_GELU_BIAS_BF16 ||
                              EPI == EPI_GELU_ADDQ_BF16)
                    ((ushortT*)Cv)[(size_t)(gr + r) * ldc + gc] = f2bf(v);
                else if constexpr (EPI == EPI_BIAS_F32)
                    ((float*)Cv)[(size_t)(gr + r) * ldc + gc] = v;
                else
                    ((ushortT*)Cv)[(size_t)gc * ldc + (gr + r)] = f2bf(v);
            }
        }
    }
}

// ---------------- fp32-grade split-bf16 GEMM, transposed bf16 out ----------
// C^T = (A @ Bt^T), A/B given as (hi,lo) bf16 splits; output Ct [N][M] bf16.
// Used to precompute combined weights Wa = W_v @ W_rt1[:d], Wb = W_v @ W_rt1[d:].
__global__ __launch_bounds__(256)
void wsplit_gemm(const ushortT* __restrict__ Ah, const ushortT* __restrict__ Al,
                 const ushortT* __restrict__ Bh, const ushortT* __restrict__ Bl,
                 ushortT* __restrict__ Ct, int K, int lda, int ldb, int ldc)
{
    __shared__ ushortT Ash[128 * 32], Asl[128 * 32];
    __shared__ ushortT Bsh[128 * 32], Bsl[128 * 32];
    const int tid  = threadIdx.x;
    const int lane = tid & 63;
    const int w    = tid >> 6;
    const int wr   = (w >> 1) * 64;
    const int wc   = (w & 1) * 64;
    const int m0   = blockIdx.y * 128;
    const int n0   = blockIdx.x * 128;
    const int lrow = lane >> 2;
    const int lk   = (lane & 3) * 8;

    f32x4 acc[4][4];
    #pragma unroll
    for (int i = 0; i < 4; i++)
        #pragma unroll
        for (int j = 0; j < 4; j++) acc[i][j] = (f32x4){0.f, 0.f, 0.f, 0.f};

    for (int kk = 0; kk < K; kk += 32) {
        #pragma unroll
        for (int i = 0; i < 2; i++) {
            const size_t aoff = (size_t)(m0 + w * 32 + i * 16 + lrow) * lda + kk + lk;
            const size_t boff = (size_t)(n0 + w * 32 + i * 16 + lrow) * ldb + kk + lk;
            const int ldst = (w * 32 + i * 16) * 32;
            gload16(Ah + aoff, &Ash[ldst]);
            gload16(Al + aoff, &Asl[ldst]);
            gload16(Bh + boff, &Bsh[ldst]);
            gload16(Bl + boff, &Bsl[ldst]);
        }
        __syncthreads();

        const int mi = lane & 15;
        const int ko = (lane >> 4) * 8;
        short8 ah[4], al[4], bh[4], bl[4];
        #pragma unroll
        for (int i = 0; i < 4; i++) {
            ah[i] = *(const short8*)&Ash[(wr + i * 16 + mi) * 32 + ko];
            al[i] = *(const short8*)&Asl[(wr + i * 16 + mi) * 32 + ko];
        }
        #pragma unroll
        for (int j = 0; j < 4; j++) {
            bh[j] = *(const short8*)&Bsh[(wc + j * 16 + mi) * 32 + ko];
            bl[j] = *(const short8*)&Bsl[(wc + j * 16 + mi) * 32 + ko];
        }
        #pragma unroll
        for (int i = 0; i < 4; i++)
            #pragma unroll
            for (int j = 0; j < 4; j++) {
                acc[i][j] = __builtin_amdgcn_mfma_f32_16x16x32_bf16(ah[i], bh[j], acc[i][j], 0, 0, 0);
                acc[i][j] = __builtin_amdgcn_mfma_f32_16x16x32_bf16(ah[i], bl[j], acc[i][j], 0, 0, 0);
                acc[i][j] = __builtin_amdgcn_mfma_f32_16x16x32_bf16(al[i], bh[j], acc[i][j], 0, 0, 0);
            }
        __syncthreads();
    }

    const int cr = (lane >> 4) * 4;
    const int cc = lane & 15;
    #pragma unroll
    for (int i = 0; i < 4; i++)
        #pragma unroll
        for (int j = 0; j < 4; j++) {
            const int gr = m0 + wr + i * 16 + cr;
            const int gc = n0 + wc + j * 16 + cc;
            #pragma unroll
            for (int r = 0; r < 4; r++)
                Ct[(size_t)gc * ldc + (gr + r)] = f2bf(acc[i][j][r]);
        }
}

// ---------------- encoder fast path: split-bf16 MFMA (fp32-grade precision) ----
__global__ __launch_bounds__(256)
void enc_gemm(const ushortT* __restrict__ Ah, const ushortT* __restrict__ Al,
              const ushortT* __restrict__ Bh, const ushortT* __restrict__ Bl,
              const float* __restrict__ bias, float* __restrict__ C)
{
    __shared__ ushortT Ash[128 * 32], Asl[128 * 32];
    __shared__ ushortT Bsh[128 * 32], Bsl[128 * 32];
    const int tid  = threadIdx.x;
    const int lane = tid & 63;
    const int w    = tid >> 6;
    const int wr   = (w >> 1) * 64;
    const int wc   = (w & 1) * 64;
    const int m0   = blockIdx.y * 128;
    const int n0   = blockIdx.x * 128;
    const int lrow = lane >> 2;
    const int lk   = (lane & 3) * 8;

    f32x4 acc[4][4];
    #pragma unroll
    for (int i = 0; i < 4; i++)
        #pragma unroll
        for (int j = 0; j < 4; j++) acc[i][j] = (f32x4){0.f, 0.f, 0.f, 0.f};

    for (int kk = 0; kk < DMODEL; kk += 32) {
        #pragma unroll
        for (int i = 0; i < 2; i++) {
            const size_t aoff = (size_t)(m0 + w * 32 + i * 16 + lrow) * DMODEL + kk + lk;
            const size_t boff = (size_t)(n0 + w * 32 + i * 16 + lrow) * DMODEL + kk + lk;
            const int ldst = (w * 32 + i * 16) * 32;
            gload16(Ah + aoff, &Ash[ldst]);
            gload16(Al + aoff, &Asl[ldst]);
            gload16(Bh + boff, &Bsh[ldst]);
            gload16(Bl + boff, &Bsl[ldst]);
        }
        __syncthreads();

        const int mi = lane & 15;
        const int ko = (lane >> 4) * 8;
        short8 ah[4], al[4], bh[4], bl[4];
        #pragma unroll
        for (int i = 0; i < 4; i++) {
            ah[i] = *(const short8*)&Ash[(wr + i * 16 + mi) * 32 + ko];
            al[i] = *(const short8*)&Asl[(wr + i * 16 + mi) * 32 + ko];
        }
        #pragma unroll
        for (int j = 0; j < 4; j++) {
            bh[j] = *(const short8*)&Bsh[(wc + j * 16 + mi) * 32 + ko];
            bl[j] = *(const short8*)&Bsl[(wc + j * 16 + mi) * 32 + ko];
        }
        #pragma unroll
        for (int i = 0; i < 4; i++)
            #pragma unroll
            for (int j = 0; j < 4; j++) {
                acc[i][j] = __builtin_amdgcn_mfma_f32_16x16x32_bf16(ah[i], bh[j], acc[i][j], 0, 0, 0);
                acc[i][j] = __builtin_amdgcn_mfma_f32_16x16x32_bf16(ah[i], bl[j], acc[i][j], 0, 0, 0);
                acc[i][j] = __builtin_amdgcn_mfma_f32_16x16x32_bf16(al[i], bh[j], acc[i][j], 0, 0, 0);
            }
        __syncthreads();
    }

    const int cr = (lane >> 4) * 4;
    const int cc = lane & 15;
    #pragma unroll
    for (int i = 0; i < 4; i++)
        #pragma unroll
        for (int j = 0; j < 4; j++) {
            const int gr = m0 + wr + i * 16 + cr;
            const int gc = n0 + wc + j * 16 + cc;
            #pragma unroll
            for (int r = 0; r < 4; r++)
                C[(size_t)(gr + r) * 512 + gc] = gelu_f(acc[i][j][r] + bias[gc]);
        }
}

// logit = gelu_row . W_re2 (fp64 accum of f32 values); flag borderline tokens
__global__ __launch_bounds__(256)
void target2_k(const float* __restrict__ Genc, const float* __restrict__ W2,
               const float* __restrict__ b2, float* __restrict__ outT,
               float* __restrict__ outS, int* __restrict__ gidx,
               int* __restrict__ cnt, int* __restrict__ list)
{
    const int m = blockIdx.x * 4 + (threadIdx.x >> 6);
    const int lane = threadIdx.x & 63;
    const float* gr = Genc + (size_t)m * 512;
    double s = 0.0;
    #pragma unroll 4
    for (int j = lane; j < 512; j += 64) s = fma((double)gr[j], (double)W2[j], s);
    #pragma unroll
    for (int off = 32; off; off >>= 1) s += __shfl_down(s, off);
    if (lane == 0) {
        double logit = s + (double)b2[0];
        double str = 1.0 / (1.0 + exp(-logit));
        double r = str * (double)(NSEQ - 1);
        double n = rint(r);
        double dist = fabs(r - n);             // distance to nearest integer
        n = fmin(fmax(n, 0.0), (double)(NSEQ - 1));
        int t = (int)n;
        outT[m] = (float)t;
        outS[m] = (float)str;
        gidx[m] = ((m >> 12) << 12) + t;
        if (dist > 0.46) {                      // within 0.04 of a .5 boundary
            int ix = atomicAdd(cnt, 1);
            list[ix] = m;
        }
    }
}

// exact fp64 recompute for flagged tokens.
#define FIX_T 2
__global__ __launch_bounds__(256)
void fixup_k(const float* __restrict__ h, const float* __restrict__ W1,
             const float* __restrict__ b1, const float* __restrict__ W2,
             const float* __restrict__ b2, const int* __restrict__ cnt_p,
             const int* __restrict__ list, float* __restrict__ outT,
             float* __restrict__ outS, int* __restrict__ gidx)
{
    __shared__ float hrow[FIX_T][1024];
    __shared__ double red[4][FIX_T];
    const int tid = threadIdx.x;
    const int cnt = *cnt_p;
    for (int base = (int)blockIdx.x * FIX_T; base < cnt;
         base += (int)gridDim.x * FIX_T) {
        const int nt = min(FIX_T, cnt - base);
        for (int t = 0; t < nt; t++) {
            const int m = list[base + t];
            const float4* src = (const float4*)(h + (size_t)m * 1024);
            ((float4*)hrow[t])[tid] = src[tid];   // 256 * 16B = 4 KB row
        }
        __syncthreads();

        double a[FIX_T][2];
        #pragma unroll
        for (int t = 0; t < FIX_T; t++) { a[t][0] = 0.0; a[t][1] = 0.0; }

        #pragma unroll 4
        for (int k = 0; k < 1024; k++) {
            const double wa = (double)W1[(size_t)k * 512 + tid];
            const double wb = (double)W1[(size_t)k * 512 + tid + 256];
            #pragma unroll
            for (int t = 0; t < FIX_T; t++) {
                const double hv = (double)hrow[t][k];
                a[t][0] = fma(hv, wa, a[t][0]);
                a[t][1] = fma(hv, wb, a[t][1]);
            }
        }

        const double w2a = (double)W2[tid], w2b = (double)W2[tid + 256];
        const double b1a = (double)b1[tid], b1b = (double)b1[tid + 256];
        const int lane = tid & 63, w = tid >> 6;
        #pragma unroll
        for (int t = 0; t < FIX_T; t++) {
            double v = w2a * gelu_d(a[t][0] + b1a) + w2b * gelu_d(a[t][1] + b1b);
            #pragma unroll
            for (int off = 32; off; off >>= 1) v += __shfl_down(v, off);
            if (lane == 0) red[w][t] = v;
        }
        __syncthreads();
        if (tid < nt) {
            const int t = tid;
            double logit = red[0][t] + red[1][t] + red[2][t] + red[3][t] + (double)b2[0];
            double str = 1.0 / (1.0 + exp(-logit));
            double r = str * (double)(NSEQ - 1);
            double n = rint(r);
            n = fmin(fmax(n, 0.0), (double)(NSEQ - 1));
            const int m = list[base + t];
            const int ti = (int)n;
            outT[m] = (float)ti;
            outS[m] = (float)str;
            gidx[m] = ((m >> 12) << 12) + ti;
        }
        __syncthreads();
    }
}

__global__ __launch_bounds__(256)
void biascomb_k(const float* __restrict__ brt2, const float* __restrict__ Wo,
                float* __restrict__ bc)
{
    int j = blockIdx.x * 256 + threadIdx.x;
    float s = 0.f;
    for (int e = 0; e < DMODEL; e++) s = fmaf(brt2[e], Wo[e * DMODEL + j], s);
    bc[j] = s;
}

// f32 -> bf16 straight cast
__global__ __launch_bounds__(256)
void cast_k(const float* __restrict__ x, ushortT* __restrict__ y, int n)
{
    int i = (blockIdx.x * 256 + threadIdx.x) * 4;
    if (i < n) {
        float4 v = *(const float4*)(x + i);
        ushortT o[4] = { f2bf(v.x), f2bf(v.y), f2bf(v.z), f2bf(v.w) };
        *(ulong1*)&y[i] = *(ulong1*)o;
    }
}

// f32 -> (hi bf16, lo bf16) 2-way split
__global__ __launch_bounds__(256)
void split_cast_k(const float* __restrict__ x, ushortT* __restrict__ yh,
                  ushortT* __restrict__ yl, int n)
{
    int i = (blockIdx.x * 256 + threadIdx.x) * 4;
    if (i < n) {
        float4 v = *(const float4*)(x + i);
        float vv[4] = { v.x, v.y, v.z, v.w };
        ushortT oh[4], ol[4];
        #pragma unroll
        for (int q = 0; q < 4; q++) {
            oh[q] = f2bf(vv[q]);
            ol[q] = f2bf(vv[q] - bf2f(oh[q]));
        }
        *(ulong1*)&yh[i] = *(ulong1*)oh;
        *(ulong1*)&yl[i] = *(ulong1*)ol;
    }
}

// W [K][N] f32 -> Wt [N][K] bf16
__global__ __launch_bounds__(256)
void transcast_k(const float* __restrict__ W, ushortT* __restrict__ Wt, int K, int N)
{
    __shared__ float t[32][33];
    const int tx = threadIdx.x & 31, ty = threadIdx.x >> 5;
    const int n0 = blockIdx.x * 32, k0 = blockIdx.y * 32;
    #pragma unroll
    for (int r = 0; r < 32; r += 8)
        t[ty + r][tx] = W[(size_t)(k0 + ty + r) * N + n0 + tx];
    __syncthreads();
    #pragma unroll
    for (int r = 0; r < 32; r += 8)
        Wt[(size_t)(n0 + ty + r) * K + k0 + tx] = f2bf(t[tx][ty + r]);
}

// W [K][N] f32 -> Wt_hi/lo [N][K] bf16 split
__global__ __launch_bounds__(256)
void split_transcast_k(const float* __restrict__ W, ushortT* __restrict__ Wth,
                       ushortT* __restrict__ Wtl, int K, int N)
{
    __shared__ float t[32][33];
    const int tx = threadIdx.x & 31, ty = threadIdx.x >> 5;
    const int n0 = blockIdx.x * 32, k0 = blockIdx.y * 32;
    #pragma unroll
    for (int r = 0; r < 32; r += 8)
        t[ty + r][tx] = W[(size_t)(k0 + ty + r) * N + n0 + tx];
    __syncthreads();
    #pragma unroll
    for (int r = 0; r < 32; r += 8) {
        float x = t[tx][ty + r];
        ushortT hi = f2bf(x);
        Wth[(size_t)(n0 + ty + r) * K + k0 + tx] = hi;
        Wtl[(size_t)(n0 + ty + r) * K + k0 + tx] = f2bf(x - bf2f(hi));
    }
}

extern "C" void kernel_launch(void* const* d_in, const int* in_sizes, int n_in,
                              void* d_out, int out_size, void* d_ws, size_t ws_size,
                              hipStream_t stream)
{
    const float* h     = (const float*)d_in[0];
    const float* W_re1 = (const float*)d_in[1];
    const float* b_re1 = (const float*)d_in[2];
    const float* W_re2 = (const float*)d_in[3];
    const float* b_re2 = (const float*)d_in[4];
    const float* W_v   = (const float*)d_in[5];
    const float* W_rt1 = (const float*)d_in[6];
    const float* b_rt1 = (const float*)d_in[7];
    const float* W_rt2 = (const float*)d_in[8];
    const float* b_rt2 = (const float*)d_in[9];
    const float* W_o   = (const float*)d_in[10];

    float* z    = (float*)d_out;                        // [16384,1024] f32
    float* outT = z + (size_t)MTOT * DMODEL;
    float* outS = outT + MTOT;
    ushortT* Q    = (ushortT*)z;                        // bf16 [16384,1024], lower 32 MB of z region
    ushortT* h_hi = (ushortT*)z + (size_t)MTOT * DMODEL;// bf16, upper 32 MB of z region

    char* ws = (char*)d_ws;
    ushortT* G       = (ushortT*)ws;                          // 32 MB  gelu(pre) bf16
    float*   Genc    = (float*)(ws + (32ull  << 20));         // 32 MB  encoder gelu f32
    ushortT* h_lo    = (ushortT*)(ws + (64ull  << 20));       // 32 MB
    ushortT* Wrt1t_h = (ushortT*)(ws + (96ull  << 20));       // 4 MB  [1024][2048]
    ushortT* Wrt1t_l = (ushortT*)(ws + (100ull << 20));       // 4 MB
    ushortT* Wv_h    = (ushortT*)(ws + (104ull << 20));       // 2 MB  [1024][1024]
    ushortT* Wv_l    = (ushortT*)(ws + (106ull << 20));       // 2 MB
    ushortT* Wa_t    = (ushortT*)(ws + (108ull << 20));       // 2 MB  (Wv@Wrt1[:d])^T bf16
    ushortT* Wb_t    = (ushortT*)(ws + (110ull << 20));       // 2 MB  (Wv@Wrt1[d:])^T bf16
    ushortT* Wo_t    = (ushortT*)(ws + (112ull << 20));       // 2 MB
    ushortT* Wrt2_b  = (ushortT*)(ws + (114ull << 20));       // 2 MB
    ushortT* Wc_t    = (ushortT*)(ws + (116ull << 20));       // 2 MB
    ushortT* Wre1t_h = (ushortT*)(ws + (118ull << 20));       // 1 MB [512][1024]
    ushortT* Wre1t_l = (ushortT*)(ws + (119ull << 20));       // 1 MB
    float*   b_c     = (float*)(ws + (120ull << 20));         // 4 KB
    int*     cnt     = (int*)  (ws + (120ull << 20) + 4096);  // 4 KB
    int*     gidx    = (int*)  (ws + (120ull << 20) + 8192);  // 64 KB
    int*     list    = (int*)  (ws + (120ull << 20) + 8192 + 65536); // 64 KB

    // --- casts / splits / transposes ---
    split_cast_k<<<dim3(MTOT * DMODEL / 1024), 256, 0, stream>>>(h, h_hi, h_lo, MTOT * DMODEL);
    split_cast_k<<<dim3(DMODEL * DMODEL / 1024), 256, 0, stream>>>(W_v, Wv_h, Wv_l, DMODEL * DMODEL);
    split_transcast_k<<<dim3(16, 32), 256, 0, stream>>>(W_re1, Wre1t_h, Wre1t_l, DMODEL, 512);
    split_transcast_k<<<dim3(32, 64), 256, 0, stream>>>(W_rt1, Wrt1t_h, Wrt1t_l, 2 * DMODEL, DMODEL);
    cast_k<<<dim3(DMODEL * DMODEL / 1024), 256, 0, stream>>>(W_rt2, Wrt2_b, DMODEL * DMODEL);
    transcast_k<<<dim3(32, 32), 256, 0, stream>>>(W_o, Wo_t, DMODEL, DMODEL);
    biascomb_k<<<dim3(4), 256, 0, stream>>>(b_rt2, W_o, b_c);

    // --- combined weights: Wa = Wv@Wrt1[:d], Wb = Wv@Wrt1[d:]  (fp32-grade, ~2.1 GF each) ---
    wsplit_gemm<<<dim3(8, 8), 256, 0, stream>>>(Wv_h, Wv_l, Wrt1t_h, Wrt1t_l,
                                                Wa_t, DMODEL, DMODEL, 2 * DMODEL, DMODEL);
    wsplit_gemm<<<dim3(8, 8), 256, 0, stream>>>(Wv_h, Wv_l, Wrt1t_h + DMODEL, Wrt1t_l + DMODEL,
                                                Wb_t, DMODEL, DMODEL, 2 * DMODEL, DMODEL);

    // --- encoder fast path (split-bf16 MFMA, fp32-grade) ---
    enc_gemm<<<dim3(4, 128), 256, 0, stream>>>(h_hi, h_lo, Wre1t_h, Wre1t_l, b_re1, Genc);

    hipMemsetAsync(cnt, 0, 4, stream);
    target2_k<<<dim3(MTOT / 4), 256, 0, stream>>>(Genc, W_re2, b_re2, outT, outS, gidx, cnt, list);
    // exact fp64 recompute of borderline tokens (~8%)
    fixup_k<<<dim3(4096), 256, 0, stream>>>(h, W_re1, b_re1, W_re2, b_re2, cnt, list,
                                            outT, outS, gidx);

    // --- z path: pre = h@Wa + gather(h@Wb) + b_rt1 ; G = gelu(pre) ; z = G@Wc + b_c ---
    mfma_gemm<EPI_TRANS_BF16><<<dim3(8, 8), 256, 0, stream>>>(
        Wrt2_b, Wo_t, nullptr, (void*)Wc_t, DMODEL, DMODEL, DMODEL, DMODEL, nullptr, nullptr);

    mfma_gemm<EPI_BF16><<<dim3(8, 128), 256, 0, stream>>>(
        h_hi, Wb_t, nullptr, (void*)Q, DMODEL, DMODEL, DMODEL, DMODEL, nullptr, nullptr);

    mfma_gemm<EPI_GELU_ADDQ_BF16><<<dim3(8, 128), 256, 0, stream>>>(
        h_hi, Wa_t, b_rt1, (void*)G, DMODEL, DMODEL, DMODEL, DMODEL, gidx, Q);

    mfma_gemm<EPI_BIAS_F32><<<dim3(8, 128), 256, 0, stream>>>(
        G, Wc_t, b_c, (void*)z, DMODEL, DMODEL, DMODEL, DMODEL, nullptr, nullptr);
}

// Round 4
// 666.091 us; speedup vs baseline: 1.0554x; 1.0554x over previous
//
#include <hip/hip_runtime.h>
#include <math.h>
#include <type_traits>

#define DMODEL 1024
#define NSEQ   4096
#define MTOT   16384

typedef unsigned short ushortT;
typedef __attribute__((ext_vector_type(8))) short short8;
typedef __attribute__((ext_vector_type(4))) float f32x4;

__device__ __forceinline__ float gelu_f(float x) {
    return 0.5f * x * (1.0f + erff(x * 0.70710678118654752440f));
}
__device__ __forceinline__ double gelu_d(double x) {
    return 0.5 * x * (1.0 + erf(x * 0.70710678118654752440));
}
__device__ __forceinline__ ushortT f2bf(float f) {
    unsigned u = __float_as_uint(f);
    u += 0x7FFFu + ((u >> 16) & 1u);   // round-to-nearest-even
    return (ushortT)(u >> 16);
}
__device__ __forceinline__ float bf2f(ushortT b) {
    return __uint_as_float(((unsigned)b) << 16);
}
// async global->LDS, 16B per lane; LDS dest = wave-uniform base + lane*16
__device__ __forceinline__ void gload16(const void* g, void* l) {
    __builtin_amdgcn_global_load_lds(
        (const __attribute__((address_space(1))) unsigned*)g,
        (__attribute__((address_space(3))) unsigned*)l, 16, 0, 0);
}

// ---------------- bf16 MFMA GEMM (m97 structure, XCD-swizzled) ----------------
// C = epi(A @ Bt^T [+bias]); A [M,K] bf16 row-major (lda), Bt [N,K] bf16 (ldb).
// cpx = nwg/8 (swizzle chunk per XCD); nwg must be a multiple of 8; gridDim.x==8.
enum { EPI_BIAS_F32 = 2, EPI_TRANS_BF16 = 3 };

template<int EPI>
__global__ __launch_bounds__(256)
void mfma_gemm(const ushortT* __restrict__ A, const ushortT* __restrict__ Bt,
               const float* __restrict__ bias, void* __restrict__ Cv,
               int K, int lda, int ldb, int ldc, int cpx)
{
    __shared__ ushortT As[128 * 32];
    __shared__ ushortT Bs[128 * 32];
    const int tid  = threadIdx.x;
    const int lane = tid & 63;
    const int w    = tid >> 6;
    const int wr   = (w >> 1) * 64;
    const int wc   = (w & 1) * 64;
    // T1: XCD-aware swizzle (8 XCDs); each XCD gets a contiguous chunk of tiles
    const int flat = blockIdx.x + (blockIdx.y << 3);
    const int swz  = (flat & 7) * cpx + (flat >> 3);
    const int n0   = (swz & 7) * 128;
    const int m0   = (swz >> 3) * 128;

    const int lrow = lane >> 2;
    const int lk   = (lane & 3) * 8;

    f32x4 acc[4][4];
    #pragma unroll
    for (int i = 0; i < 4; i++)
        #pragma unroll
        for (int j = 0; j < 4; j++) acc[i][j] = (f32x4){0.f, 0.f, 0.f, 0.f};

    for (int kk = 0; kk < K; kk += 32) {
        #pragma unroll
        for (int i = 0; i < 2; i++) {
            const ushortT* ga = A + (size_t)(m0 + w * 32 + i * 16 + lrow) * lda + kk + lk;
            gload16(ga, &As[(w * 32 + i * 16) * 32]);
            const ushortT* gb = Bt + (size_t)(n0 + w * 32 + i * 16 + lrow) * ldb + kk + lk;
            gload16(gb, &Bs[(w * 32 + i * 16) * 32]);
        }
        __syncthreads();

        const int mi = lane & 15;
        const int ko = (lane >> 4) * 8;
        short8 a[4], b[4];
        #pragma unroll
        for (int i = 0; i < 4; i++)
            a[i] = *(const short8*)&As[(wr + i * 16 + mi) * 32 + ko];
        #pragma unroll
        for (int j = 0; j < 4; j++)
            b[j] = *(const short8*)&Bs[(wc + j * 16 + mi) * 32 + ko];
        #pragma unroll
        for (int i = 0; i < 4; i++)
            #pragma unroll
            for (int j = 0; j < 4; j++)
                acc[i][j] = __builtin_amdgcn_mfma_f32_16x16x32_bf16(a[i], b[j], acc[i][j], 0, 0, 0);
        __syncthreads();
    }

    const int cr = (lane >> 4) * 4;
    const int cc = lane & 15;
    #pragma unroll
    for (int i = 0; i < 4; i++) {
        #pragma unroll
        for (int j = 0; j < 4; j++) {
            const int gr = m0 + wr + i * 16 + cr;
            const int gc = n0 + wc + j * 16 + cc;
            #pragma unroll
            for (int r = 0; r < 4; r++) {
                float v = acc[i][j][r];
                if constexpr (EPI == EPI_BIAS_F32)
                    ((float*)Cv)[(size_t)(gr + r) * ldc + gc] = v + bias[gc];
                else
                    ((ushortT*)Cv)[(size_t)gc * ldc + (gr + r)] = f2bf(v);
            }
        }
    }
}

// ---------------- fused PQ GEMM: A-shared dual-B dual-output -------------------
// P = A@Wa^T + bias (f32),  Q = A@Wb^T (bf16).  A [M,1024] bf16; Ba/Bb [1024][1024] bf16.
// grid (8,128), 256 thr. Stages A once per K-step for both outputs (32 MFMA/step).
__global__ __launch_bounds__(256)
void pq_gemm(const ushortT* __restrict__ A, const ushortT* __restrict__ Ba,
             const ushortT* __restrict__ Bb, const float* __restrict__ bias,
             float* __restrict__ P, ushortT* __restrict__ Q)
{
    __shared__ ushortT As[128 * 32];
    __shared__ ushortT Bsa[128 * 32];
    __shared__ ushortT Bsb[128 * 32];
    const int tid  = threadIdx.x;
    const int lane = tid & 63;
    const int w    = tid >> 6;
    const int wr   = (w >> 1) * 64;
    const int wc   = (w & 1) * 64;
    const int flat = blockIdx.x + (blockIdx.y << 3);       // nwg = 1024
    const int swz  = (flat & 7) * 128 + (flat >> 3);
    const int n0   = (swz & 7) * 128;
    const int m0   = (swz >> 3) * 128;

    const int lrow = lane >> 2;
    const int lk   = (lane & 3) * 8;

    f32x4 acc_a[4][4], acc_b[4][4];
    #pragma unroll
    for (int i = 0; i < 4; i++)
        #pragma unroll
        for (int j = 0; j < 4; j++) {
            acc_a[i][j] = (f32x4){0.f, 0.f, 0.f, 0.f};
            acc_b[i][j] = (f32x4){0.f, 0.f, 0.f, 0.f};
        }

    for (int kk = 0; kk < DMODEL; kk += 32) {
        #pragma unroll
        for (int i = 0; i < 2; i++) {
            const int row = w * 32 + i * 16;
            gload16(A  + (size_t)(m0 + row + lrow) * DMODEL + kk + lk, &As[row * 32]);
            gload16(Ba + (size_t)(n0 + row + lrow) * DMODEL + kk + lk, &Bsa[row * 32]);
            gload16(Bb + (size_t)(n0 + row + lrow) * DMODEL + kk + lk, &Bsb[row * 32]);
        }
        __syncthreads();

        const int mi = lane & 15;
        const int ko = (lane >> 4) * 8;
        short8 a[4];
        #pragma unroll
        for (int i = 0; i < 4; i++)
            a[i] = *(const short8*)&As[(wr + i * 16 + mi) * 32 + ko];
        #pragma unroll
        for (int j = 0; j < 4; j++) {
            short8 ba = *(const short8*)&Bsa[(wc + j * 16 + mi) * 32 + ko];
            short8 bb = *(const short8*)&Bsb[(wc + j * 16 + mi) * 32 + ko];
            #pragma unroll
            for (int i = 0; i < 4; i++) {
                acc_a[i][j] = __builtin_amdgcn_mfma_f32_16x16x32_bf16(a[i], ba, acc_a[i][j], 0, 0, 0);
                acc_b[i][j] = __builtin_amdgcn_mfma_f32_16x16x32_bf16(a[i], bb, acc_b[i][j], 0, 0, 0);
            }
        }
        __syncthreads();
    }

    const int cr = (lane >> 4) * 4;
    const int cc = lane & 15;
    #pragma unroll
    for (int i = 0; i < 4; i++) {
        #pragma unroll
        for (int j = 0; j < 4; j++) {
            const int gr = m0 + wr + i * 16 + cr;
            const int gc = n0 + wc + j * 16 + cc;
            #pragma unroll
            for (int r = 0; r < 4; r++) {
                P[(size_t)(gr + r) * DMODEL + gc] = acc_a[i][j][r] + bias[gc];
                Q[(size_t)(gr + r) * DMODEL + gc] = f2bf(acc_b[i][j][r]);
            }
        }
    }
}

// ---------------- row-granular gather + gelu:  G[m] = bf16(gelu(P[m] + Q[gidx[m]])) ----
__global__ __launch_bounds__(256)
void gelu_gather_k(const float* __restrict__ P, const ushortT* __restrict__ Q,
                   const int* __restrict__ gidx, ushortT* __restrict__ G)
{
    const int m = blockIdx.x;
    int t = gidx[m];                             // wave-uniform per block
    t = max(0, min(t, MTOT - 1));                // defensive clamp (poison-proof)
    const int c = threadIdx.x * 4;
    float4 p = *(const float4*)(P + (size_t)m * DMODEL + c);
    ushort4 q = *(const ushort4*)(Q + (size_t)t * DMODEL + c);
    ushortT o[4];
    o[0] = f2bf(gelu_f(p.x + bf2f(q.x)));
    o[1] = f2bf(gelu_f(p.y + bf2f(q.y)));
    o[2] = f2bf(gelu_f(p.z + bf2f(q.z)));
    o[3] = f2bf(gelu_f(p.w + bf2f(q.w)));
    *(ulong1*)(G + (size_t)m * DMODEL + c) = *(ulong1*)o;
}

// ---------------- fp32-grade split-bf16 GEMM, transposed bf16 out ----------
// Combined launch: grid (8,16); blockIdx.y>=8 selects the Wb half (K-offset +1024).
// Ct layout [N][M] so it plugs straight in as the Bt operand of pq_gemm.
__global__ __launch_bounds__(256)
void wsplit_gemm(const ushortT* __restrict__ Ah, const ushortT* __restrict__ Al,
                 const ushortT* __restrict__ Bh0, const ushortT* __restrict__ Bl0,
                 ushortT* __restrict__ Ct0, int K, int lda, int ldb, int ldc)
{
    __shared__ ushortT Ash[128 * 32], Asl[128 * 32];
    __shared__ ushortT Bsh[128 * 32], Bsl[128 * 32];
    const int tid  = threadIdx.x;
    const int lane = tid & 63;
    const int w    = tid >> 6;
    const int wr   = (w >> 1) * 64;
    const int wc   = (w & 1) * 64;
    const int sel  = blockIdx.y >> 3;
    const int m0   = (blockIdx.y & 7) * 128;
    const int n0   = blockIdx.x * 128;
    const ushortT* Bh = Bh0 + sel * 1024;        // K-offset into Wrt1t (ldb = 2048)
    const ushortT* Bl = Bl0 + sel * 1024;
    ushortT* Ct = Ct0 + (size_t)sel * 1024 * 1024;
    const int lrow = lane >> 2;
    const int lk   = (lane & 3) * 8;

    f32x4 acc[4][4];
    #pragma unroll
    for (int i = 0; i < 4; i++)
        #pragma unroll
        for (int j = 0; j < 4; j++) acc[i][j] = (f32x4){0.f, 0.f, 0.f, 0.f};

    for (int kk = 0; kk < K; kk += 32) {
        #pragma unroll
        for (int i = 0; i < 2; i++) {
            const size_t aoff = (size_t)(m0 + w * 32 + i * 16 + lrow) * lda + kk + lk;
            const size_t boff = (size_t)(n0 + w * 32 + i * 16 + lrow) * ldb + kk + lk;
            const int ldst = (w * 32 + i * 16) * 32;
            gload16(Ah + aoff, &Ash[ldst]);
            gload16(Al + aoff, &Asl[ldst]);
            gload16(Bh + boff, &Bsh[ldst]);
            gload16(Bl + boff, &Bsl[ldst]);
        }
        __syncthreads();

        const int mi = lane & 15;
        const int ko = (lane >> 4) * 8;
        short8 ah[4], al[4], bh[4], bl[4];
        #pragma unroll
        for (int i = 0; i < 4; i++) {
            ah[i] = *(const short8*)&Ash[(wr + i * 16 + mi) * 32 + ko];
            al[i] = *(const short8*)&Asl[(wr + i * 16 + mi) * 32 + ko];
        }
        #pragma unroll
        for (int j = 0; j < 4; j++) {
            bh[j] = *(const short8*)&Bsh[(wc + j * 16 + mi) * 32 + ko];
            bl[j] = *(const short8*)&Bsl[(wc + j * 16 + mi) * 32 + ko];
        }
        #pragma unroll
        for (int i = 0; i < 4; i++)
            #pragma unroll
            for (int j = 0; j < 4; j++) {
                acc[i][j] = __builtin_amdgcn_mfma_f32_16x16x32_bf16(ah[i], bh[j], acc[i][j], 0, 0, 0);
                acc[i][j] = __builtin_amdgcn_mfma_f32_16x16x32_bf16(ah[i], bl[j], acc[i][j], 0, 0, 0);
                acc[i][j] = __builtin_amdgcn_mfma_f32_16x16x32_bf16(al[i], bh[j], acc[i][j], 0, 0, 0);
            }
        __syncthreads();
    }

    const int cr = (lane >> 4) * 4;
    const int cc = lane & 15;
    #pragma unroll
    for (int i = 0; i < 4; i++)
        #pragma unroll
        for (int j = 0; j < 4; j++) {
            const int gr = m0 + wr + i * 16 + cr;
            const int gc = n0 + wc + j * 16 + cc;
            #pragma unroll
            for (int r = 0; r < 4; r++)
                Ct[(size_t)gc * ldc + (gr + r)] = f2bf(acc[i][j][r]);
        }
}

// ---------------- encoder fast path: split-bf16 MFMA (fp32-grade precision) ----
// grid (4,128), XCD-swizzled.
__global__ __launch_bounds__(256)
void enc_gemm(const ushortT* __restrict__ Ah, const ushortT* __restrict__ Al,
              const ushortT* __restrict__ Bh, const ushortT* __restrict__ Bl,
              const float* __restrict__ bias, float* __restrict__ C)
{
    __shared__ ushortT Ash[128 * 32], Asl[128 * 32];
    __shared__ ushortT Bsh[128 * 32], Bsl[128 * 32];
    const int tid  = threadIdx.x;
    const int lane = tid & 63;
    const int w    = tid >> 6;
    const int wr   = (w >> 1) * 64;
    const int wc   = (w & 1) * 64;
    const int flat = blockIdx.x + (blockIdx.y << 2);       // nwg = 512
    const int swz  = (flat & 7) * 64 + (flat >> 3);
    const int n0   = (swz & 3) * 128;
    const int m0   = (swz >> 2) * 128;
    const int lrow = lane >> 2;
    const int lk   = (lane & 3) * 8;

    f32x4 acc[4][4];
    #pragma unroll
    for (int i = 0; i < 4; i++)
        #pragma unroll
        for (int j = 0; j < 4; j++) acc[i][j] = (f32x4){0.f, 0.f, 0.f, 0.f};

    for (int kk = 0; kk < DMODEL; kk += 32) {
        #pragma unroll
        for (int i = 0; i < 2; i++) {
            const size_t aoff = (size_t)(m0 + w * 32 + i * 16 + lrow) * DMODEL + kk + lk;
            const size_t boff = (size_t)(n0 + w * 32 + i * 16 + lrow) * DMODEL + kk + lk;
            const int ldst = (w * 32 + i * 16) * 32;
            gload16(Ah + aoff, &Ash[ldst]);
            gload16(Al + aoff, &Asl[ldst]);
            gload16(Bh + boff, &Bsh[ldst]);
            gload16(Bl + boff, &Bsl[ldst]);
        }
        __syncthreads();

        const int mi = lane & 15;
        const int ko = (lane >> 4) * 8;
        short8 ah[4], al[4], bh[4], bl[4];
        #pragma unroll
        for (int i = 0; i < 4; i++) {
            ah[i] = *(const short8*)&Ash[(wr + i * 16 + mi) * 32 + ko];
            al[i] = *(const short8*)&Asl[(wr + i * 16 + mi) * 32 + ko];
        }
        #pragma unroll
        for (int j = 0; j < 4; j++) {
            bh[j] = *(const short8*)&Bsh[(wc + j * 16 + mi) * 32 + ko];
            bl[j] = *(const short8*)&Bsl[(wc + j * 16 + mi) * 32 + ko];
        }
        #pragma unroll
        for (int i = 0; i < 4; i++)
            #pragma unroll
            for (int j = 0; j < 4; j++) {
                acc[i][j] = __builtin_amdgcn_mfma_f32_16x16x32_bf16(ah[i], bh[j], acc[i][j], 0, 0, 0);
                acc[i][j] = __builtin_amdgcn_mfma_f32_16x16x32_bf16(ah[i], bl[j], acc[i][j], 0, 0, 0);
                acc[i][j] = __builtin_amdgcn_mfma_f32_16x16x32_bf16(al[i], bh[j], acc[i][j], 0, 0, 0);
            }
        __syncthreads();
    }

    const int cr = (lane >> 4) * 4;
    const int cc = lane & 15;
    #pragma unroll
    for (int i = 0; i < 4; i++)
        #pragma unroll
        for (int j = 0; j < 4; j++) {
            const int gr = m0 + wr + i * 16 + cr;
            const int gc = n0 + wc + j * 16 + cc;
            #pragma unroll
            for (int r = 0; r < 4; r++)
                C[(size_t)(gr + r) * 512 + gc] = gelu_f(acc[i][j][r] + bias[gc]);
        }
}

// logit = gelu_row . W_re2 (fp64 accum of f32 values); flag borderline tokens
__global__ __launch_bounds__(256)
void target2_k(const float* __restrict__ Genc, const float* __restrict__ W2,
               const float* __restrict__ b2, float* __restrict__ outT,
               float* __restrict__ outS, int* __restrict__ gidx,
               int* __restrict__ cnt, int* __restrict__ list)
{
    const int m = blockIdx.x * 4 + (threadIdx.x >> 6);
    const int lane = threadIdx.x & 63;
    const float* gr = Genc + (size_t)m * 512;
    double s = 0.0;
    #pragma unroll 4
    for (int j = lane; j < 512; j += 64) s = fma((double)gr[j], (double)W2[j], s);
    #pragma unroll
    for (int off = 32; off; off >>= 1) s += __shfl_down(s, off);
    if (lane == 0) {
        double logit = s + (double)b2[0];
        double str = 1.0 / (1.0 + exp(-logit));
        double r = str * (double)(NSEQ - 1);
        double n = rint(r);
        double dist = fabs(r - n);             // distance to nearest integer
        n = fmin(fmax(n, 0.0), (double)(NSEQ - 1));
        int t = (int)n;
        outT[m] = (float)t;
        outS[m] = (float)str;
        gidx[m] = ((m >> 12) << 12) + t;
        if (dist > 0.46) {                      // within 0.04 of a .5 boundary
            int ix = atomicAdd(cnt, 1) & (MTOT - 1);   // defensive mask (list is 64KB)
            list[ix] = m;
        }
    }
}

// exact fp64 recompute for flagged tokens.
// FIX_T=4: amortizes the per-block 2MB W1 stream over 4 tokens.
#define FIX_T 4
__global__ __launch_bounds__(256)
void fixup_k(const float* __restrict__ h, const float* __restrict__ W1,
             const float* __restrict__ b1, const float* __restrict__ W2,
             const float* __restrict__ b2, const int* __restrict__ cnt_p,
             const int* __restrict__ list, float* __restrict__ outT,
             float* __restrict__ outS, int* __restrict__ gidx)
{
    __shared__ float hrow[FIX_T][1024];
    __shared__ double red[4][FIX_T];
    const int tid = threadIdx.x;
    const int cnt = min(*cnt_p, MTOT);           // defensive clamp
    for (int base = (int)blockIdx.x * FIX_T; base < cnt;
         base += (int)gridDim.x * FIX_T) {
        const int nt = min(FIX_T, cnt - base);
        for (int t = 0; t < nt; t++) {
            const int m = list[base + t];
            const float4* src = (const float4*)(h + (size_t)m * 1024);
            ((float4*)hrow[t])[tid] = src[tid];   // 256 * 16B = 4 KB row
        }
        __syncthreads();

        double a[FIX_T][2];
        #pragma unroll
        for (int t = 0; t < FIX_T; t++) { a[t][0] = 0.0; a[t][1] = 0.0; }

        #pragma unroll 4
        for (int k = 0; k < 1024; k++) {
            const double wa = (double)W1[(size_t)k * 512 + tid];
            const double wb = (double)W1[(size_t)k * 512 + tid + 256];
            #pragma unroll
            for (int t = 0; t < FIX_T; t++) {
                const double hv = (double)hrow[t][k];
                a[t][0] = fma(hv, wa, a[t][0]);
                a[t][1] = fma(hv, wb, a[t][1]);
            }
        }

        const double w2a = (double)W2[tid], w2b = (double)W2[tid + 256];
        const double b1a = (double)b1[tid], b1b = (double)b1[tid + 256];
        const int lane = tid & 63, w = tid >> 6;
        #pragma unroll
        for (int t = 0; t < FIX_T; t++) {
            double v = w2a * gelu_d(a[t][0] + b1a) + w2b * gelu_d(a[t][1] + b1b);
            #pragma unroll
            for (int off = 32; off; off >>= 1) v += __shfl_down(v, off);
            if (lane == 0) red[w][t] = v;
        }
        __syncthreads();
        if (tid < nt) {
            const int t = tid;
            double logit = red[0][t] + red[1][t] + red[2][t] + red[3][t] + (double)b2[0];
            double str = 1.0 / (1.0 + exp(-logit));
            double r = str * (double)(NSEQ - 1);
            double n = rint(r);
            n = fmin(fmax(n, 0.0), (double)(NSEQ - 1));
            const int m = list[base + t];
            const int ti = (int)n;
            outT[m] = (float)ti;
            outS[m] = (float)str;
            gidx[m] = ((m >> 12) << 12) + ti;
        }
        __syncthreads();
    }
}

__global__ __launch_bounds__(256)
void biascomb_k(const float* __restrict__ brt2, const float* __restrict__ Wo,
                float* __restrict__ bc)
{
    int j = blockIdx.x * 256 + threadIdx.x;
    float s = 0.f;
    for (int e = 0; e < DMODEL; e++) s = fmaf(brt2[e], Wo[e * DMODEL + j], s);
    bc[j] = s;
}

// f32 -> bf16 straight cast
__global__ __launch_bounds__(256)
void cast_k(const float* __restrict__ x, ushortT* __restrict__ y, int n)
{
    int i = (blockIdx.x * 256 + threadIdx.x) * 4;
    if (i < n) {
        float4 v = *(const float4*)(x + i);
        ushortT o[4] = { f2bf(v.x), f2bf(v.y), f2bf(v.z), f2bf(v.w) };
        *(ulong1*)&y[i] = *(ulong1*)o;
    }
}

// f32 -> (hi bf16, lo bf16) 2-way split
__global__ __launch_bounds__(256)
void split_cast_k(const float* __restrict__ x, ushortT* __restrict__ yh,
                  ushortT* __restrict__ yl, int n)
{
    int i = (blockIdx.x * 256 + threadIdx.x) * 4;
    if (i < n) {
        float4 v = *(const float4*)(x + i);
        float vv[4] = { v.x, v.y, v.z, v.w };
        ushortT oh[4], ol[4];
        #pragma unroll
        for (int q = 0; q < 4; q++) {
            oh[q] = f2bf(vv[q]);
            ol[q] = f2bf(vv[q] - bf2f(oh[q]));
        }
        *(ulong1*)&yh[i] = *(ulong1*)oh;
        *(ulong1*)&yl[i] = *(ulong1*)ol;
    }
}

// W [K][N] f32 -> Wt [N][K] bf16
__global__ __launch_bounds__(256)
void transcast_k(const float* __restrict__ W, ushortT* __restrict__ Wt, int K, int N)
{
    __shared__ float t[32][33];
    const int tx = threadIdx.x & 31, ty = threadIdx.x >> 5;
    const int n0 = blockIdx.x * 32, k0 = blockIdx.y * 32;
    #pragma unroll
    for (int r = 0; r < 32; r += 8)
        t[ty + r][tx] = W[(size_t)(k0 + ty + r) * N + n0 + tx];
    __syncthreads();
    #pragma unroll
    for (int r = 0; r < 32; r += 8)
        Wt[(size_t)(n0 + ty + r) * K + k0 + tx] = f2bf(t[tx][ty + r]);
}

// W [K][N] f32 -> Wt_hi/lo [N][K] bf16 split
__global__ __launch_bounds__(256)
void split_transcast_k(const float* __restrict__ W, ushortT* __restrict__ Wth,
                       ushortT* __restrict__ Wtl, int K, int N)
{
    __shared__ float t[32][33];
    const int tx = threadIdx.x & 31, ty = threadIdx.x >> 5;
    const int n0 = blockIdx.x * 32, k0 = blockIdx.y * 32;
    #pragma unroll
    for (int r = 0; r < 32; r += 8)
        t[ty + r][tx] = W[(size_t)(k0 + ty + r) * N + n0 + tx];
    __syncthreads();
    #pragma unroll
    for (int r = 0; r < 32; r += 8) {
        float x = t[tx][ty + r];
        ushortT hi = f2bf(x);
        Wth[(size_t)(n0 + ty + r) * K + k0 + tx] = hi;
        Wtl[(size_t)(n0 + ty + r) * K + k0 + tx] = f2bf(x - bf2f(hi));
    }
}

extern "C" void kernel_launch(void* const* d_in, const int* in_sizes, int n_in,
                              void* d_out, int out_size, void* d_ws, size_t ws_size,
                              hipStream_t stream)
{
    const float* h     = (const float*)d_in[0];
    const float* W_re1 = (const float*)d_in[1];
    const float* b_re1 = (const float*)d_in[2];
    const float* W_re2 = (const float*)d_in[3];
    const float* b_re2 = (const float*)d_in[4];
    const float* W_v   = (const float*)d_in[5];
    const float* W_rt1 = (const float*)d_in[6];
    const float* b_rt1 = (const float*)d_in[7];
    const float* W_rt2 = (const float*)d_in[8];
    const float* b_rt2 = (const float*)d_in[9];
    const float* W_o   = (const float*)d_in[10];

    float* z    = (float*)d_out;                        // [16384,1024] f32
    float* outT = z + (size_t)MTOT * DMODEL;
    float* outS = outT + MTOT;
    ushortT* Q    = (ushortT*)z;                        // bf16 [16384,1024], lower 32 MB of z region
    ushortT* h_hi = (ushortT*)z + (size_t)MTOT * DMODEL;// bf16, upper 32 MB of z region

    char* ws = (char*)d_ws;
    ushortT* G       = (ushortT*)ws;                          // 32 MB  gelu(pre) bf16
    float*   Genc    = (float*)(ws + (32ull  << 20));         // 32 MB  encoder gelu f32 (freed after target2)
    ushortT* h_lo    = (ushortT*)(ws + (64ull  << 20));       // 32 MB  (freed after enc_gemm)
    float*   P       = (float*)(ws + (32ull  << 20));         // 64 MB  pre-act f32, REUSES Genc+h_lo region
    ushortT* Wrt1t_h = (ushortT*)(ws + (96ull  << 20));       // 4 MB  [1024][2048]
    ushortT* Wrt1t_l = (ushortT*)(ws + (100ull << 20));       // 4 MB
    ushortT* Wv_h    = (ushortT*)(ws + (104ull << 20));       // 2 MB  [1024][1024]
    ushortT* Wv_l    = (ushortT*)(ws + (106ull << 20));       // 2 MB
    ushortT* Wa_t    = (ushortT*)(ws + (108ull << 20));       // 2 MB  (Wv@Wrt1[:d])^T bf16
    // Wb_t lives at Wa_t + 1M elements (contiguous) = ws + 110 MB
    ushortT* Wo_t    = (ushortT*)(ws + (112ull << 20));       // 2 MB
    ushortT* Wrt2_b  = (ushortT*)(ws + (114ull << 20));       // 2 MB
    ushortT* Wc_t    = (ushortT*)(ws + (116ull << 20));       // 2 MB
    ushortT* Wre1t_h = (ushortT*)(ws + (118ull << 20));       // 1 MB [512][1024]
    ushortT* Wre1t_l = (ushortT*)(ws + (119ull << 20));       // 1 MB
    float*   b_c     = (float*)(ws + (120ull << 20));         // 4 KB
    int*     cnt     = (int*)  (ws + (120ull << 20) + 4096);  // 4 KB
    int*     gidx    = (int*)  (ws + (120ull << 20) + 8192);  // 64 KB
    int*     list    = (int*)  (ws + (120ull << 20) + 8192 + 65536); // 64 KB
    ushortT* Wb_t    = Wa_t + (size_t)1024 * 1024;

    // --- casts / splits / transposes ---
    split_cast_k<<<dim3(MTOT * DMODEL / 1024), 256, 0, stream>>>(h, h_hi, h_lo, MTOT * DMODEL);
    split_cast_k<<<dim3(DMODEL * DMODEL / 1024), 256, 0, stream>>>(W_v, Wv_h, Wv_l, DMODEL * DMODEL);
    split_transcast_k<<<dim3(16, 32), 256, 0, stream>>>(W_re1, Wre1t_h, Wre1t_l, DMODEL, 512);
    split_transcast_k<<<dim3(32, 64), 256, 0, stream>>>(W_rt1, Wrt1t_h, Wrt1t_l, 2 * DMODEL, DMODEL);
    cast_k<<<dim3(DMODEL * DMODEL / 1024), 256, 0, stream>>>(W_rt2, Wrt2_b, DMODEL * DMODEL);
    transcast_k<<<dim3(32, 32), 256, 0, stream>>>(W_o, Wo_t, DMODEL, DMODEL);
    biascomb_k<<<dim3(4), 256, 0, stream>>>(b_rt2, W_o, b_c);

    // --- combined weights Wa|Wb in ONE launch (fp32-grade; 128 blocks) ---
    wsplit_gemm<<<dim3(8, 16), 256, 0, stream>>>(Wv_h, Wv_l, Wrt1t_h, Wrt1t_l,
                                                 Wa_t, DMODEL, DMODEL, 2 * DMODEL, DMODEL);

    // --- encoder fast path (split-bf16 MFMA, fp32-grade) ---
    enc_gemm<<<dim3(4, 128), 256, 0, stream>>>(h_hi, h_lo, Wre1t_h, Wre1t_l, b_re1, Genc);

    hipMemsetAsync(cnt, 0, 4, stream);
    target2_k<<<dim3(MTOT / 4), 256, 0, stream>>>(Genc, W_re2, b_re2, outT, outS, gidx, cnt, list);
    // exact fp64 recompute of borderline tokens (~8%)
    fixup_k<<<dim3(4096), 256, 0, stream>>>(h, W_re1, b_re1, W_re2, b_re2, cnt, list,
                                            outT, outS, gidx);

    // --- z path: P = h@Wa + b_rt1 (f32), Q = h@Wb (bf16)  [A-shared fused GEMM] ---
    mfma_gemm<EPI_TRANS_BF16><<<dim3(8, 8), 256, 0, stream>>>(
        Wrt2_b, Wo_t, nullptr, (void*)Wc_t, DMODEL, DMODEL, DMODEL, DMODEL, 8);

    pq_gemm<<<dim3(8, 128), 256, 0, stream>>>(h_hi, Wa_t, Wb_t, b_rt1, P, Q);

    // G = bf16(gelu(P + Q[gidx]))  — row-granular coalesced gather
    gelu_gather_k<<<dim3(MTOT), 256, 0, stream>>>(P, Q, gidx, G);

    // z = G @ Wc + b_c
    mfma_gemm<EPI_BIAS_F32><<<dim3(8, 128), 256, 0, stream>>>(
        G, Wc_t, b_c, (void*)z, DMODEL, DMODEL, DMODEL, DMODEL, 128);
}

// Round 5
// 644.957 us; speedup vs baseline: 1.0900x; 1.0328x over previous
//
#include <hip/hip_runtime.h>
#include <math.h>
#include <type_traits>

#define DMODEL 1024
#define NSEQ   4096
#define MTOT   16384

typedef unsigned short ushortT;
typedef __attribute__((ext_vector_type(8))) short short8;
typedef __attribute__((ext_vector_type(4))) float f32x4;

__device__ __forceinline__ float gelu_f(float x) {
    return 0.5f * x * (1.0f + erff(x * 0.70710678118654752440f));
}
__device__ __forceinline__ double gelu_d(double x) {
    return 0.5 * x * (1.0 + erf(x * 0.70710678118654752440));
}
__device__ __forceinline__ ushortT f2bf(float f) {
    unsigned u = __float_as_uint(f);
    u += 0x7FFFu + ((u >> 16) & 1u);   // round-to-nearest-even
    return (ushortT)(u >> 16);
}
__device__ __forceinline__ float bf2f(ushortT b) {
    return __uint_as_float(((unsigned)b) << 16);
}
// async global->LDS, 16B per lane; LDS dest = wave-uniform base + lane*16
__device__ __forceinline__ void gload16(const void* g, void* l) {
    __builtin_amdgcn_global_load_lds(
        (const __attribute__((address_space(1))) unsigned*)g,
        (__attribute__((address_space(3))) unsigned*)l, 16, 0, 0);
}

// ---------------- bf16 MFMA GEMM (m97 structure, XCD-swizzled) ----------------
// C = epi(A @ Bt^T [+bias]); A [M,K] bf16 row-major (lda), Bt [N,K] bf16 (ldb).
// NXT = n-tiles (gridDim.x); cpx = nwg/8; nwg must be a multiple of 8.
// EPI_PQ: N=2048 over [Wa;Wb] — cols <1024 -> P=acc+bias (f32, Cv); cols >=1024
//         -> Q=bf16(acc) (Cv2). Branch is block-uniform (128-col tiles).
enum { EPI_BIAS_F32 = 2, EPI_TRANS_BF16 = 3, EPI_PQ = 5 };

template<int EPI, int NXT>
__global__ __launch_bounds__(256)
void mfma_gemm(const ushortT* __restrict__ A, const ushortT* __restrict__ Bt,
               const float* __restrict__ bias, void* __restrict__ Cv,
               void* __restrict__ Cv2, int K, int lda, int ldb, int ldc, int cpx)
{
    __shared__ ushortT As[128 * 32];
    __shared__ ushortT Bs[128 * 32];
    const int tid  = threadIdx.x;
    const int lane = tid & 63;
    const int w    = tid >> 6;
    const int wr   = (w >> 1) * 64;
    const int wc   = (w & 1) * 64;
    // T1: XCD-aware swizzle (8 XCDs); each XCD gets a contiguous chunk of tiles
    const int flat = blockIdx.x + blockIdx.y * NXT;
    const int swz  = (flat & 7) * cpx + (flat >> 3);
    const int n0   = (swz & (NXT - 1)) * 128;
    const int m0   = (swz / NXT) * 128;

    const int lrow = lane >> 2;
    const int lk   = (lane & 3) * 8;

    f32x4 acc[4][4];
    #pragma unroll
    for (int i = 0; i < 4; i++)
        #pragma unroll
        for (int j = 0; j < 4; j++) acc[i][j] = (f32x4){0.f, 0.f, 0.f, 0.f};

    for (int kk = 0; kk < K; kk += 32) {
        #pragma unroll
        for (int i = 0; i < 2; i++) {
            const ushortT* ga = A + (size_t)(m0 + w * 32 + i * 16 + lrow) * lda + kk + lk;
            gload16(ga, &As[(w * 32 + i * 16) * 32]);
            const ushortT* gb = Bt + (size_t)(n0 + w * 32 + i * 16 + lrow) * ldb + kk + lk;
            gload16(gb, &Bs[(w * 32 + i * 16) * 32]);
        }
        __syncthreads();

        const int mi = lane & 15;
        const int ko = (lane >> 4) * 8;
        short8 a[4], b[4];
        #pragma unroll
        for (int i = 0; i < 4; i++)
            a[i] = *(const short8*)&As[(wr + i * 16 + mi) * 32 + ko];
        #pragma unroll
        for (int j = 0; j < 4; j++)
            b[j] = *(const short8*)&Bs[(wc + j * 16 + mi) * 32 + ko];
        #pragma unroll
        for (int i = 0; i < 4; i++)
            #pragma unroll
            for (int j = 0; j < 4; j++)
                acc[i][j] = __builtin_amdgcn_mfma_f32_16x16x32_bf16(a[i], b[j], acc[i][j], 0, 0, 0);
        __syncthreads();
    }

    const int cr = (lane >> 4) * 4;
    const int cc = lane & 15;
    #pragma unroll
    for (int i = 0; i < 4; i++) {
        #pragma unroll
        for (int j = 0; j < 4; j++) {
            const int gr = m0 + wr + i * 16 + cr;
            const int gc = n0 + wc + j * 16 + cc;
            #pragma unroll
            for (int r = 0; r < 4; r++) {
                float v = acc[i][j][r];
                if constexpr (EPI == EPI_BIAS_F32) {
                    ((float*)Cv)[(size_t)(gr + r) * ldc + gc] = v + bias[gc];
                } else if constexpr (EPI == EPI_PQ) {
                    if (gc < 1024)
                        ((float*)Cv)[(size_t)(gr + r) * ldc + gc] = v + bias[gc];
                    else
                        ((ushortT*)Cv2)[(size_t)(gr + r) * ldc + (gc - 1024)] = f2bf(v);
                } else {
                    ((ushortT*)Cv)[(size_t)gc * ldc + (gr + r)] = f2bf(v);
                }
            }
        }
    }
}

// ---------------- row-granular gather + gelu:  G[m] = bf16(gelu(P[m] + Q[gidx[m]])) ----
__global__ __launch_bounds__(256)
void gelu_gather_k(const float* __restrict__ P, const ushortT* __restrict__ Q,
                   const int* __restrict__ gidx, ushortT* __restrict__ G)
{
    const int m = blockIdx.x;
    int t = gidx[m];                             // wave-uniform per block
    t = max(0, min(t, MTOT - 1));                // defensive clamp (poison-proof)
    const int c = threadIdx.x * 4;
    float4 p = *(const float4*)(P + (size_t)m * DMODEL + c);
    ushort4 q = *(const ushort4*)(Q + (size_t)t * DMODEL + c);
    ushortT o[4];
    o[0] = f2bf(gelu_f(p.x + bf2f(q.x)));
    o[1] = f2bf(gelu_f(p.y + bf2f(q.y)));
    o[2] = f2bf(gelu_f(p.z + bf2f(q.z)));
    o[3] = f2bf(gelu_f(p.w + bf2f(q.w)));
    *(ulong1*)(G + (size_t)m * DMODEL + c) = *(ulong1*)o;
}

// ---------------- fp32-grade split-bf16 GEMM, transposed bf16 out ----------
// Combined launch: grid (8,16); blockIdx.y>=8 selects the Wb half (K-offset +1024).
// Ct layout [N][M]: sel=0 writes rows 0..1023 (Wa^T), sel=1 rows 1024..2047 (Wb^T),
// producing the contiguous [2048][1024] Bt operand for the PQ GEMM.
__global__ __launch_bounds__(256)
void wsplit_gemm(const ushortT* __restrict__ Ah, const ushortT* __restrict__ Al,
                 const ushortT* __restrict__ Bh0, const ushortT* __restrict__ Bl0,
                 ushortT* __restrict__ Ct0, int K, int lda, int ldb, int ldc)
{
    __shared__ ushortT Ash[128 * 32], Asl[128 * 32];
    __shared__ ushortT Bsh[128 * 32], Bsl[128 * 32];
    const int tid  = threadIdx.x;
    const int lane = tid & 63;
    const int w    = tid >> 6;
    const int wr   = (w >> 1) * 64;
    const int wc   = (w & 1) * 64;
    const int sel  = blockIdx.y >> 3;
    const int m0   = (blockIdx.y & 7) * 128;
    const int n0   = blockIdx.x * 128;
    const ushortT* Bh = Bh0 + sel * 1024;        // K-offset into Wrt1t (ldb = 2048)
    const ushortT* Bl = Bl0 + sel * 1024;
    ushortT* Ct = Ct0 + (size_t)sel * 1024 * 1024;
    const int lrow = lane >> 2;
    const int lk   = (lane & 3) * 8;

    f32x4 acc[4][4];
    #pragma unroll
    for (int i = 0; i < 4; i++)
        #pragma unroll
        for (int j = 0; j < 4; j++) acc[i][j] = (f32x4){0.f, 0.f, 0.f, 0.f};

    for (int kk = 0; kk < K; kk += 32) {
        #pragma unroll
        for (int i = 0; i < 2; i++) {
            const size_t aoff = (size_t)(m0 + w * 32 + i * 16 + lrow) * lda + kk + lk;
            const size_t boff = (size_t)(n0 + w * 32 + i * 16 + lrow) * ldb + kk + lk;
            const int ldst = (w * 32 + i * 16) * 32;
            gload16(Ah + aoff, &Ash[ldst]);
            gload16(Al + aoff, &Asl[ldst]);
            gload16(Bh + boff, &Bsh[ldst]);
            gload16(Bl + boff, &Bsl[ldst]);
        }
        __syncthreads();

        const int mi = lane & 15;
        const int ko = (lane >> 4) * 8;
        short8 ah[4], al[4], bh[4], bl[4];
        #pragma unroll
        for (int i = 0; i < 4; i++) {
            ah[i] = *(const short8*)&Ash[(wr + i * 16 + mi) * 32 + ko];
            al[i] = *(const short8*)&Asl[(wr + i * 16 + mi) * 32 + ko];
        }
        #pragma unroll
        for (int j = 0; j < 4; j++) {
            bh[j] = *(const short8*)&Bsh[(wc + j * 16 + mi) * 32 + ko];
            bl[j] = *(const short8*)&Bsl[(wc + j * 16 + mi) * 32 + ko];
        }
        #pragma unroll
        for (int i = 0; i < 4; i++)
            #pragma unroll
            for (int j = 0; j < 4; j++) {
                acc[i][j] = __builtin_amdgcn_mfma_f32_16x16x32_bf16(ah[i], bh[j], acc[i][j], 0, 0, 0);
                acc[i][j] = __builtin_amdgcn_mfma_f32_16x16x32_bf16(ah[i], bl[j], acc[i][j], 0, 0, 0);
                acc[i][j] = __builtin_amdgcn_mfma_f32_16x16x32_bf16(al[i], bh[j], acc[i][j], 0, 0, 0);
            }
        __syncthreads();
    }

    const int cr = (lane >> 4) * 4;
    const int cc = lane & 15;
    #pragma unroll
    for (int i = 0; i < 4; i++)
        #pragma unroll
        for (int j = 0; j < 4; j++) {
            const int gr = m0 + wr + i * 16 + cr;
            const int gc = n0 + wc + j * 16 + cc;
            #pragma unroll
            for (int r = 0; r < 4; r++)
                Ct[(size_t)gc * ldc + (gr + r)] = f2bf(acc[i][j][r]);
        }
}

// ---------------- encoder fast path: split-bf16 MFMA (fp32-grade precision) ----
// grid (4,128), XCD-swizzled.
__global__ __launch_bounds__(256)
void enc_gemm(const ushortT* __restrict__ Ah, const ushortT* __restrict__ Al,
              const ushortT* __restrict__ Bh, const ushortT* __restrict__ Bl,
              const float* __restrict__ bias, float* __restrict__ C)
{
    __shared__ ushortT Ash[128 * 32], Asl[128 * 32];
    __shared__ ushortT Bsh[128 * 32], Bsl[128 * 32];
    const int tid  = threadIdx.x;
    const int lane = tid & 63;
    const int w    = tid >> 6;
    const int wr   = (w >> 1) * 64;
    const int wc   = (w & 1) * 64;
    const int flat = blockIdx.x + (blockIdx.y << 2);       // nwg = 512
    const int swz  = (flat & 7) * 64 + (flat >> 3);
    const int n0   = (swz & 3) * 128;
    const int m0   = (swz >> 2) * 128;
    const int lrow = lane >> 2;
    const int lk   = (lane & 3) * 8;

    f32x4 acc[4][4];
    #pragma unroll
    for (int i = 0; i < 4; i++)
        #pragma unroll
        for (int j = 0; j < 4; j++) acc[i][j] = (f32x4){0.f, 0.f, 0.f, 0.f};

    for (int kk = 0; kk < DMODEL; kk += 32) {
        #pragma unroll
        for (int i = 0; i < 2; i++) {
            const size_t aoff = (size_t)(m0 + w * 32 + i * 16 + lrow) * DMODEL + kk + lk;
            const size_t boff = (size_t)(n0 + w * 32 + i * 16 + lrow) * DMODEL + kk + lk;
            const int ldst = (w * 32 + i * 16) * 32;
            gload16(Ah + aoff, &Ash[ldst]);
            gload16(Al + aoff, &Asl[ldst]);
            gload16(Bh + boff, &Bsh[ldst]);
            gload16(Bl + boff, &Bsl[ldst]);
        }
        __syncthreads();

        const int mi = lane & 15;
        const int ko = (lane >> 4) * 8;
        short8 ah[4], al[4], bh[4], bl[4];
        #pragma unroll
        for (int i = 0; i < 4; i++) {
            ah[i] = *(const short8*)&Ash[(wr + i * 16 + mi) * 32 + ko];
            al[i] = *(const short8*)&Asl[(wr + i * 16 + mi) * 32 + ko];
        }
        #pragma unroll
        for (int j = 0; j < 4; j++) {
            bh[j] = *(const short8*)&Bsh[(wc + j * 16 + mi) * 32 + ko];
            bl[j] = *(const short8*)&Bsl[(wc + j * 16 + mi) * 32 + ko];
        }
        #pragma unroll
        for (int i = 0; i < 4; i++)
            #pragma unroll
            for (int j = 0; j < 4; j++) {
                acc[i][j] = __builtin_amdgcn_mfma_f32_16x16x32_bf16(ah[i], bh[j], acc[i][j], 0, 0, 0);
                acc[i][j] = __builtin_amdgcn_mfma_f32_16x16x32_bf16(ah[i], bl[j], acc[i][j], 0, 0, 0);
                acc[i][j] = __builtin_amdgcn_mfma_f32_16x16x32_bf16(al[i], bh[j], acc[i][j], 0, 0, 0);
            }
        __syncthreads();
    }

    const int cr = (lane >> 4) * 4;
    const int cc = lane & 15;
    #pragma unroll
    for (int i = 0; i < 4; i++)
        #pragma unroll
        for (int j = 0; j < 4; j++) {
            const int gr = m0 + wr + i * 16 + cr;
            const int gc = n0 + wc + j * 16 + cc;
            #pragma unroll
            for (int r = 0; r < 4; r++)
                C[(size_t)(gr + r) * 512 + gc] = gelu_f(acc[i][j][r] + bias[gc]);
        }
}

// logit = gelu_row . W_re2 (fp64 accum of f32 values); flag borderline tokens
__global__ __launch_bounds__(256)
void target2_k(const float* __restrict__ Genc, const float* __restrict__ W2,
               const float* __restrict__ b2, float* __restrict__ outT,
               float* __restrict__ outS, int* __restrict__ gidx,
               int* __restrict__ cnt, int* __restrict__ list)
{
    const int m = blockIdx.x * 4 + (threadIdx.x >> 6);
    const int lane = threadIdx.x & 63;
    const float* gr = Genc + (size_t)m * 512;
    double s = 0.0;
    #pragma unroll 4
    for (int j = lane; j < 512; j += 64) s = fma((double)gr[j], (double)W2[j], s);
    #pragma unroll
    for (int off = 32; off; off >>= 1) s += __shfl_down(s, off);
    if (lane == 0) {
        double logit = s + (double)b2[0];
        double str = 1.0 / (1.0 + exp(-logit));
        double r = str * (double)(NSEQ - 1);
        double n = rint(r);
        double dist = fabs(r - n);             // distance to nearest integer
        n = fmin(fmax(n, 0.0), (double)(NSEQ - 1));
        int t = (int)n;
        outT[m] = (float)t;
        outS[m] = (float)str;
        gidx[m] = ((m >> 12) << 12) + t;
        if (dist > 0.46) {                      // within 0.04 of a .5 boundary
            int ix = atomicAdd(cnt, 1) & (MTOT - 1);   // defensive mask (list is 64KB)
            list[ix] = m;
        }
    }
}

// exact fp64 recompute for flagged tokens.
// FIX_T=4: amortizes the per-block 2MB W1 stream over 4 tokens.
#define FIX_T 4
__global__ __launch_bounds__(256)
void fixup_k(const float* __restrict__ h, const float* __restrict__ W1,
             const float* __restrict__ b1, const float* __restrict__ W2,
             const float* __restrict__ b2, const int* __restrict__ cnt_p,
             const int* __restrict__ list, float* __restrict__ outT,
             float* __restrict__ outS, int* __restrict__ gidx)
{
    __shared__ float hrow[FIX_T][1024];
    __shared__ double red[4][FIX_T];
    const int tid = threadIdx.x;
    const int cnt = min(*cnt_p, MTOT);           // defensive clamp
    for (int base = (int)blockIdx.x * FIX_T; base < cnt;
         base += (int)gridDim.x * FIX_T) {
        const int nt = min(FIX_T, cnt - base);
        for (int t = 0; t < nt; t++) {
            const int m = list[base + t];
            const float4* src = (const float4*)(h + (size_t)m * 1024);
            ((float4*)hrow[t])[tid] = src[tid];   // 256 * 16B = 4 KB row
        }
        __syncthreads();

        double a[FIX_T][2];
        #pragma unroll
        for (int t = 0; t < FIX_T; t++) { a[t][0] = 0.0; a[t][1] = 0.0; }

        #pragma unroll 4
        for (int k = 0; k < 1024; k++) {
            const double wa = (double)W1[(size_t)k * 512 + tid];
            const double wb = (double)W1[(size_t)k * 512 + tid + 256];
            #pragma unroll
            for (int t = 0; t < FIX_T; t++) {
                const double hv = (double)hrow[t][k];
                a[t][0] = fma(hv, wa, a[t][0]);
                a[t][1] = fma(hv, wb, a[t][1]);
            }
        }

        const double w2a = (double)W2[tid], w2b = (double)W2[tid + 256];
        const double b1a = (double)b1[tid], b1b = (double)b1[tid + 256];
        const int lane = tid & 63, w = tid >> 6;
        #pragma unroll
        for (int t = 0; t < FIX_T; t++) {
            double v = w2a * gelu_d(a[t][0] + b1a) + w2b * gelu_d(a[t][1] + b1b);
            #pragma unroll
            for (int off = 32; off; off >>= 1) v += __shfl_down(v, off);
            if (lane == 0) red[w][t] = v;
        }
        __syncthreads();
        if (tid < nt) {
            const int t = tid;
            double logit = red[0][t] + red[1][t] + red[2][t] + red[3][t] + (double)b2[0];
            double str = 1.0 / (1.0 + exp(-logit));
            double r = str * (double)(NSEQ - 1);
            double n = rint(r);
            n = fmin(fmax(n, 0.0), (double)(NSEQ - 1));
            const int m = list[base + t];
            const int ti = (int)n;
            outT[m] = (float)ti;
            outS[m] = (float)str;
            gidx[m] = ((m >> 12) << 12) + ti;
        }
        __syncthreads();
    }
}

__global__ __launch_bounds__(256)
void biascomb_k(const float* __restrict__ brt2, const float* __restrict__ Wo,
                float* __restrict__ bc)
{
    int j = blockIdx.x * 256 + threadIdx.x;
    float s = 0.f;
    for (int e = 0; e < DMODEL; e++) s = fmaf(brt2[e], Wo[e * DMODEL + j], s);
    bc[j] = s;
}

// f32 -> bf16 straight cast
__global__ __launch_bounds__(256)
void cast_k(const float* __restrict__ x, ushortT* __restrict__ y, int n)
{
    int i = (blockIdx.x * 256 + threadIdx.x) * 4;
    if (i < n) {
        float4 v = *(const float4*)(x + i);
        ushortT o[4] = { f2bf(v.x), f2bf(v.y), f2bf(v.z), f2bf(v.w) };
        *(ulong1*)&y[i] = *(ulong1*)o;
    }
}

// f32 -> (hi bf16, lo bf16) 2-way split
__global__ __launch_bounds__(256)
void split_cast_k(const float* __restrict__ x, ushortT* __restrict__ yh,
                  ushortT* __restrict__ yl, int n)
{
    int i = (blockIdx.x * 256 + threadIdx.x) * 4;
    if (i < n) {
        float4 v = *(const float4*)(x + i);
        float vv[4] = { v.x, v.y, v.z, v.w };
        ushortT oh[4], ol[4];
        #pragma unroll
        for (int q = 0; q < 4; q++) {
            oh[q] = f2bf(vv[q]);
            ol[q] = f2bf(vv[q] - bf2f(oh[q]));
        }
        *(ulong1*)&yh[i] = *(ulong1*)oh;
        *(ulong1*)&yl[i] = *(ulong1*)ol;
    }
}

// W [K][N] f32 -> Wt [N][K] bf16
__global__ __launch_bounds__(256)
void transcast_k(const float* __restrict__ W, ushortT* __restrict__ Wt, int K, int N)
{
    __shared__ float t[32][33];
    const int tx = threadIdx.x & 31, ty = threadIdx.x >> 5;
    const int n0 = blockIdx.x * 32, k0 = blockIdx.y * 32;
    #pragma unroll
    for (int r = 0; r < 32; r += 8)
        t[ty + r][tx] = W[(size_t)(k0 + ty + r) * N + n0 + tx];
    __syncthreads();
    #pragma unroll
    for (int r = 0; r < 32; r += 8)
        Wt[(size_t)(n0 + ty + r) * K + k0 + tx] = f2bf(t[tx][ty + r]);
}

// W [K][N] f32 -> Wt_hi/lo [N][K] bf16 split
__global__ __launch_bounds__(256)
void split_transcast_k(const float* __restrict__ W, ushortT* __restrict__ Wth,
                       ushortT* __restrict__ Wtl, int K, int N)
{
    __shared__ float t[32][33];
    const int tx = threadIdx.x & 31, ty = threadIdx.x >> 5;
    const int n0 = blockIdx.x * 32, k0 = blockIdx.y * 32;
    #pragma unroll
    for (int r = 0; r < 32; r += 8)
        t[ty + r][tx] = W[(size_t)(k0 + ty + r) * N + n0 + tx];
    __syncthreads();
    #pragma unroll
    for (int r = 0; r < 32; r += 8) {
        float x = t[tx][ty + r];
        ushortT hi = f2bf(x);
        Wth[(size_t)(n0 + ty + r) * K + k0 + tx] = hi;
        Wtl[(size_t)(n0 + ty + r) * K + k0 + tx] = f2bf(x - bf2f(hi));
    }
}

extern "C" void kernel_launch(void* const* d_in, const int* in_sizes, int n_in,
                              void* d_out, int out_size, void* d_ws, size_t ws_size,
                              hipStream_t stream)
{
    const float* h     = (const float*)d_in[0];
    const float* W_re1 = (const float*)d_in[1];
    const float* b_re1 = (const float*)d_in[2];
    const float* W_re2 = (const float*)d_in[3];
    const float* b_re2 = (const float*)d_in[4];
    const float* W_v   = (const float*)d_in[5];
    const float* W_rt1 = (const float*)d_in[6];
    const float* b_rt1 = (const float*)d_in[7];
    const float* W_rt2 = (const float*)d_in[8];
    const float* b_rt2 = (const float*)d_in[9];
    const float* W_o   = (const float*)d_in[10];

    float* z    = (float*)d_out;                        // [16384,1024] f32
    float* outT = z + (size_t)MTOT * DMODEL;
    float* outS = outT + MTOT;
    ushortT* Q    = (ushortT*)z;                        // bf16 [16384,1024], lower 32 MB of z region
    ushortT* h_hi = (ushortT*)z + (size_t)MTOT * DMODEL;// bf16, upper 32 MB of z region

    char* ws = (char*)d_ws;
    ushortT* G       = (ushortT*)ws;                          // 32 MB  gelu(pre) bf16
    float*   Genc    = (float*)(ws + (32ull  << 20));         // 32 MB  encoder gelu f32 (freed after target2)
    ushortT* h_lo    = (ushortT*)(ws + (64ull  << 20));       // 32 MB  (freed after enc_gemm)
    float*   P       = (float*)(ws + (32ull  << 20));         // 64 MB  pre-act f32, REUSES Genc+h_lo region
    ushortT* Wrt1t_h = (ushortT*)(ws + (96ull  << 20));       // 4 MB  [1024][2048]
    ushortT* Wrt1t_l = (ushortT*)(ws + (100ull << 20));       // 4 MB
    ushortT* Wv_h    = (ushortT*)(ws + (104ull << 20));       // 2 MB  [1024][1024]
    ushortT* Wv_l    = (ushortT*)(ws + (106ull << 20));       // 2 MB
    ushortT* Wa_t    = (ushortT*)(ws + (108ull << 20));       // 4 MB  [Wa;Wb]^T bf16 [2048][1024]
    ushortT* Wo_t    = (ushortT*)(ws + (112ull << 20));       // 2 MB
    ushortT* Wrt2_b  = (ushortT*)(ws + (114ull << 20));       // 2 MB
    ushortT* Wc_t    = (ushortT*)(ws + (116ull << 20));       // 2 MB
    ushortT* Wre1t_h = (ushortT*)(ws + (118ull << 20));       // 1 MB [512][1024]
    ushortT* Wre1t_l = (ushortT*)(ws + (119ull << 20));       // 1 MB
    float*   b_c     = (float*)(ws + (120ull << 20));         // 4 KB
    int*     cnt     = (int*)  (ws + (120ull << 20) + 4096);  // 4 KB
    int*     gidx    = (int*)  (ws + (120ull << 20) + 8192);  // 64 KB
    int*     list    = (int*)  (ws + (120ull << 20) + 8192 + 65536); // 64 KB

    // --- casts / splits / transposes ---
    split_cast_k<<<dim3(MTOT * DMODEL / 1024), 256, 0, stream>>>(h, h_hi, h_lo, MTOT * DMODEL);
    split_cast_k<<<dim3(DMODEL * DMODEL / 1024), 256, 0, stream>>>(W_v, Wv_h, Wv_l, DMODEL * DMODEL);
    split_transcast_k<<<dim3(16, 32), 256, 0, stream>>>(W_re1, Wre1t_h, Wre1t_l, DMODEL, 512);
    split_transcast_k<<<dim3(32, 64), 256, 0, stream>>>(W_rt1, Wrt1t_h, Wrt1t_l, 2 * DMODEL, DMODEL);
    cast_k<<<dim3(DMODEL * DMODEL / 1024), 256, 0, stream>>>(W_rt2, Wrt2_b, DMODEL * DMODEL);
    transcast_k<<<dim3(32, 32), 256, 0, stream>>>(W_o, Wo_t, DMODEL, DMODEL);
    biascomb_k<<<dim3(4), 256, 0, stream>>>(b_rt2, W_o, b_c);

    // --- combined weights [Wa;Wb]^T in ONE launch (fp32-grade; 128 blocks) ---
    wsplit_gemm<<<dim3(8, 16), 256, 0, stream>>>(Wv_h, Wv_l, Wrt1t_h, Wrt1t_l,
                                                 Wa_t, DMODEL, DMODEL, 2 * DMODEL, DMODEL);

    // --- encoder fast path (split-bf16 MFMA, fp32-grade) ---
    enc_gemm<<<dim3(4, 128), 256, 0, stream>>>(h_hi, h_lo, Wre1t_h, Wre1t_l, b_re1, Genc);

    hipMemsetAsync(cnt, 0, 4, stream);
    target2_k<<<dim3(MTOT / 4), 256, 0, stream>>>(Genc, W_re2, b_re2, outT, outS, gidx, cnt, list);
    // exact fp64 recompute of borderline tokens (~8%)
    fixup_k<<<dim3(4096), 256, 0, stream>>>(h, W_re1, b_re1, W_re2, b_re2, cnt, list,
                                            outT, outS, gidx);

    // --- z path: [P|Q] = h @ [Wa;Wb]^T as ONE N=2048 GEMM (72-VGPR m97 kernel) ---
    mfma_gemm<EPI_TRANS_BF16, 8><<<dim3(8, 8), 256, 0, stream>>>(
        Wrt2_b, Wo_t, nullptr, (void*)Wc_t, nullptr, DMODEL, DMODEL, DMODEL, DMODEL, 8);

    mfma_gemm<EPI_PQ, 16><<<dim3(16, 128), 256, 0, stream>>>(
        h_hi, Wa_t, b_rt1, (void*)P, (void*)Q, DMODEL, DMODEL, DMODEL, DMODEL, 256);

    // G = bf16(gelu(P + Q[gidx]))  — row-granular coalesced gather
    gelu_gather_k<<<dim3(MTOT), 256, 0, stream>>>(P, Q, gidx, G);

    // z = G @ Wc + b_c
    mfma_gemm<EPI_BIAS_F32, 8><<<dim3(8, 128), 256, 0, stream>>>(
        G, Wc_t, b_c, (void*)z, nullptr, DMODEL, DMODEL, DMODEL, DMODEL, 128);
}

// Round 6
// 626.680 us; speedup vs baseline: 1.1218x; 1.0292x over previous
//
#include <hip/hip_runtime.h>
#include <math.h>
#include <type_traits>

#define DMODEL 1024
#define NSEQ   4096
#define MTOT   16384

typedef unsigned short ushortT;
typedef __attribute__((ext_vector_type(8))) short short8;
typedef __attribute__((ext_vector_type(4))) float f32x4;

__device__ __forceinline__ float gelu_f(float x) {
    return 0.5f * x * (1.0f + erff(x * 0.70710678118654752440f));
}
__device__ __forceinline__ double gelu_d(double x) {
    return 0.5 * x * (1.0 + erf(x * 0.70710678118654752440));
}
__device__ __forceinline__ ushortT f2bf(float f) {
    unsigned u = __float_as_uint(f);
    u += 0x7FFFu + ((u >> 16) & 1u);   // round-to-nearest-even
    return (ushortT)(u >> 16);
}
__device__ __forceinline__ float bf2f(ushortT b) {
    return __uint_as_float(((unsigned)b) << 16);
}
// async global->LDS, 16B per lane; LDS dest = wave-uniform base + lane*16
__device__ __forceinline__ void gload16(const void* g, void* l) {
    __builtin_amdgcn_global_load_lds(
        (const __attribute__((address_space(1))) unsigned*)g,
        (__attribute__((address_space(3))) unsigned*)l, 16, 0, 0);
}

enum { EPI_BIAS_F32 = 2, EPI_TRANS_BF16 = 3, EPI_PQ = 5 };

// ---------------- 256x256 8-wave pipelined GEMM (T3+T4+T5, linear LDS) -------
// C = epi(A @ Bt^T [+bias]); A [M,K] bf16 (lda), Bt [N,K] bf16 (ldb). K%64==0.
// 512 thr = 8 waves (2M x 4N); BK=64; LDS 128 KiB double-buffered.
// Counted vmcnt(2) once per K-tile keeps next-tile loads in flight across
// barriers (never drains to 0 in the main loop); raw s_barrier (no implicit
// vmcnt(0) drain).  Accumulation order per fragment identical to the m97
// kernel -> bit-identical results.
template<int EPI, int NXT>
__global__ __launch_bounds__(512, 2)
void pipe_gemm(const ushortT* __restrict__ A, const ushortT* __restrict__ Bt,
               const float* __restrict__ bias, void* __restrict__ Cv,
               void* __restrict__ Cv2, int K, int lda, int ldb, int ldc, int cpx)
{
    // [A0 | A1 | B0 | B1], each 256*64 bf16 = 32 KiB
    __shared__ ushortT smem[4 * 16384];
    const int tid  = threadIdx.x;            // 0..511
    const int lane = tid & 63;
    const int w    = tid >> 6;               // 0..7
    const int wr   = w >> 2;                 // 0..1 : M half (128 rows)
    const int wc   = w & 3;                  // 0..3 : N quarter (64 cols)
    const int flat = blockIdx.x + blockIdx.y * NXT;
    const int swz  = (flat & 7) * cpx + (flat >> 3);   // XCD swizzle (nwg%8==0)
    const int n0   = (swz & (NXT - 1)) * 256;
    const int m0   = (swz / NXT) * 256;

    // staging map: issue q covers tile rows [q*64, q*64+64); thread -> row tid/8,
    // 16B at col (tid&7)*8.  LDS dest = wave-uniform base + lane*16 (linear).
    const int srow = tid >> 3;
    const int scol = (tid & 7) * 8;

#define STG_A(buf, q, k0) gload16(A  + (size_t)(m0 + (q)*64 + srow) * lda + (k0) + scol, \
                                  (char*)smem + (buf)*32768 + (q)*8192 + w*1024)
#define STG_B(buf, q, k0) gload16(Bt + (size_t)(n0 + (q)*64 + srow) * ldb + (k0) + scol, \
                                  (char*)smem + 65536 + (buf)*32768 + (q)*8192 + w*1024)
#define BAR() asm volatile("s_barrier" ::: "memory")

    f32x4 acc[8][4];
    #pragma unroll
    for (int i = 0; i < 8; i++)
        #pragma unroll
        for (int j = 0; j < 4; j++) acc[i][j] = (f32x4){0.f, 0.f, 0.f, 0.f};

    const int NT = K >> 6;                   // K-tiles of 64

    // prologue: stage tile 0 into buf 0 (8 loads/wave)
    #pragma unroll
    for (int q = 0; q < 4; q++) { STG_A(0, q, 0); STG_B(0, q, 0); }

    const int mi = lane & 15;
    const int k8 = (lane >> 4) * 8;

    for (int t = 0; t < NT; ++t) {
        const int c  = t & 1;
        const int nb = c ^ 1;
        const int kn = (t + 1) << 6;
        const bool hn = (t + 1 < NT);

        // ---- phase 0: stage 2, counted wait, sync, B frags + A quad 0 ----
        if (hn) {
            STG_A(nb, 0, kn); STG_A(nb, 1, kn);
            asm volatile("s_waitcnt vmcnt(2)" ::: "memory");  // tile t fully landed
        } else {
            asm volatile("s_waitcnt vmcnt(0)" ::: "memory");
        }
        BAR();

        short8 bf[4][2];
        #pragma unroll
        for (int nf = 0; nf < 4; nf++)
            #pragma unroll
            for (int ks = 0; ks < 2; ks++)
                bf[nf][ks] = *(const short8*)&smem[32768 + c * 16384 +
                                (wc * 64 + nf * 16 + mi) * 64 + ks * 32 + k8];

        #pragma unroll
        for (int p = 0; p < 4; p++) {
            if (p > 0) {
                if (hn) {
                    if (p == 1) { STG_A(nb, 2, kn); STG_A(nb, 3, kn); }
                    if (p == 2) { STG_B(nb, 0, kn); STG_B(nb, 1, kn); }
                    if (p == 3) { STG_B(nb, 2, kn); STG_B(nb, 3, kn); }
                }
                BAR();
            }
            short8 af[2][2];
            #pragma unroll
            for (int ii = 0; ii < 2; ii++)
                #pragma unroll
                for (int ks = 0; ks < 2; ks++)
                    af[ii][ks] = *(const short8*)&smem[c * 16384 +
                                    (wr * 128 + (p * 2 + ii) * 16 + mi) * 64 + ks * 32 + k8];
            __builtin_amdgcn_s_setprio(1);
            #pragma unroll
            for (int ks = 0; ks < 2; ks++)
                #pragma unroll
                for (int ii = 0; ii < 2; ii++)
                    #pragma unroll
                    for (int nf = 0; nf < 4; nf++)
                        acc[p * 2 + ii][nf] = __builtin_amdgcn_mfma_f32_16x16x32_bf16(
                            af[ii][ks], bf[nf][ks], acc[p * 2 + ii][nf], 0, 0, 0);
            __builtin_amdgcn_s_setprio(0);
        }
        BAR();   // all reads of buf c done before next iter's stage overwrites it
    }

    const int cr = (lane >> 4) * 4;
    #pragma unroll
    for (int i = 0; i < 8; i++) {
        #pragma unroll
        for (int j = 0; j < 4; j++) {
            const int gr = m0 + wr * 128 + i * 16 + cr;
            const int gc = n0 + wc * 64 + j * 16 + mi;
            #pragma unroll
            for (int r = 0; r < 4; r++) {
                float v = acc[i][j][r];
                if constexpr (EPI == EPI_BIAS_F32) {
                    ((float*)Cv)[(size_t)(gr + r) * ldc + gc] = v + bias[gc];
                } else {   // EPI_PQ: cols <1024 -> P (f32+bias), else -> Q (bf16)
                    if (gc < 1024)
                        ((float*)Cv)[(size_t)(gr + r) * ldc + gc] = v + bias[gc];
                    else
                        ((ushortT*)Cv2)[(size_t)(gr + r) * ldc + (gc - 1024)] = f2bf(v);
                }
            }
        }
    }
#undef STG_A
#undef STG_B
#undef BAR
}

// ---------------- bf16 MFMA GEMM (m97 structure, XCD-swizzled) ----------------
// Retained for the small Wc_t transpose GEMM.
template<int EPI, int NXT>
__global__ __launch_bounds__(256)
void mfma_gemm(const ushortT* __restrict__ A, const ushortT* __restrict__ Bt,
               const float* __restrict__ bias, void* __restrict__ Cv,
               void* __restrict__ Cv2, int K, int lda, int ldb, int ldc, int cpx)
{
    __shared__ ushortT As[128 * 32];
    __shared__ ushortT Bs[128 * 32];
    const int tid  = threadIdx.x;
    const int lane = tid & 63;
    const int w    = tid >> 6;
    const int wr   = (w >> 1) * 64;
    const int wc   = (w & 1) * 64;
    const int flat = blockIdx.x + blockIdx.y * NXT;
    const int swz  = (flat & 7) * cpx + (flat >> 3);
    const int n0   = (swz & (NXT - 1)) * 128;
    const int m0   = (swz / NXT) * 128;

    const int lrow = lane >> 2;
    const int lk   = (lane & 3) * 8;

    f32x4 acc[4][4];
    #pragma unroll
    for (int i = 0; i < 4; i++)
        #pragma unroll
        for (int j = 0; j < 4; j++) acc[i][j] = (f32x4){0.f, 0.f, 0.f, 0.f};

    for (int kk = 0; kk < K; kk += 32) {
        #pragma unroll
        for (int i = 0; i < 2; i++) {
            const ushortT* ga = A + (size_t)(m0 + w * 32 + i * 16 + lrow) * lda + kk + lk;
            gload16(ga, &As[(w * 32 + i * 16) * 32]);
            const ushortT* gb = Bt + (size_t)(n0 + w * 32 + i * 16 + lrow) * ldb + kk + lk;
            gload16(gb, &Bs[(w * 32 + i * 16) * 32]);
        }
        __syncthreads();

        const int mi = lane & 15;
        const int ko = (lane >> 4) * 8;
        short8 a[4], b[4];
        #pragma unroll
        for (int i = 0; i < 4; i++)
            a[i] = *(const short8*)&As[(wr + i * 16 + mi) * 32 + ko];
        #pragma unroll
        for (int j = 0; j < 4; j++)
            b[j] = *(const short8*)&Bs[(wc + j * 16 + mi) * 32 + ko];
        #pragma unroll
        for (int i = 0; i < 4; i++)
            #pragma unroll
            for (int j = 0; j < 4; j++)
                acc[i][j] = __builtin_amdgcn_mfma_f32_16x16x32_bf16(a[i], b[j], acc[i][j], 0, 0, 0);
        __syncthreads();
    }

    const int cr = (lane >> 4) * 4;
    const int cc = lane & 15;
    #pragma unroll
    for (int i = 0; i < 4; i++) {
        #pragma unroll
        for (int j = 0; j < 4; j++) {
            const int gr = m0 + wr + i * 16 + cr;
            const int gc = n0 + wc + j * 16 + cc;
            #pragma unroll
            for (int r = 0; r < 4; r++) {
                float v = acc[i][j][r];
                if constexpr (EPI == EPI_BIAS_F32)
                    ((float*)Cv)[(size_t)(gr + r) * ldc + gc] = v + bias[gc];
                else
                    ((ushortT*)Cv)[(size_t)gc * ldc + (gr + r)] = f2bf(v);
            }
        }
    }
}

// ---------------- row-granular gather + gelu:  G[m] = bf16(gelu(P[m] + Q[gidx[m]])) ----
__global__ __launch_bounds__(256)
void gelu_gather_k(const float* __restrict__ P, const ushortT* __restrict__ Q,
                   const int* __restrict__ gidx, ushortT* __restrict__ G)
{
    const int m = blockIdx.x;
    int t = gidx[m];                             // wave-uniform per block
    t = max(0, min(t, MTOT - 1));                // defensive clamp (poison-proof)
    const int c = threadIdx.x * 4;
    float4 p = *(const float4*)(P + (size_t)m * DMODEL + c);
    ushort4 q = *(const ushort4*)(Q + (size_t)t * DMODEL + c);
    ushortT o[4];
    o[0] = f2bf(gelu_f(p.x + bf2f(q.x)));
    o[1] = f2bf(gelu_f(p.y + bf2f(q.y)));
    o[2] = f2bf(gelu_f(p.z + bf2f(q.z)));
    o[3] = f2bf(gelu_f(p.w + bf2f(q.w)));
    *(ulong1*)(G + (size_t)m * DMODEL + c) = *(ulong1*)o;
}

// ---------------- fp32-grade split-bf16 GEMM, transposed bf16 out ----------
// Combined launch: grid (8,16); blockIdx.y>=8 selects the Wb half (K-offset +1024).
__global__ __launch_bounds__(256)
void wsplit_gemm(const ushortT* __restrict__ Ah, const ushortT* __restrict__ Al,
                 const ushortT* __restrict__ Bh0, const ushortT* __restrict__ Bl0,
                 ushortT* __restrict__ Ct0, int K, int lda, int ldb, int ldc)
{
    __shared__ ushortT Ash[128 * 32], Asl[128 * 32];
    __shared__ ushortT Bsh[128 * 32], Bsl[128 * 32];
    const int tid  = threadIdx.x;
    const int lane = tid & 63;
    const int w    = tid >> 6;
    const int wr   = (w >> 1) * 64;
    const int wc   = (w & 1) * 64;
    const int sel  = blockIdx.y >> 3;
    const int m0   = (blockIdx.y & 7) * 128;
    const int n0   = blockIdx.x * 128;
    const ushortT* Bh = Bh0 + sel * 1024;        // K-offset into Wrt1t (ldb = 2048)
    const ushortT* Bl = Bl0 + sel * 1024;
    ushortT* Ct = Ct0 + (size_t)sel * 1024 * 1024;
    const int lrow = lane >> 2;
    const int lk   = (lane & 3) * 8;

    f32x4 acc[4][4];
    #pragma unroll
    for (int i = 0; i < 4; i++)
        #pragma unroll
        for (int j = 0; j < 4; j++) acc[i][j] = (f32x4){0.f, 0.f, 0.f, 0.f};

    for (int kk = 0; kk < K; kk += 32) {
        #pragma unroll
        for (int i = 0; i < 2; i++) {
            const size_t aoff = (size_t)(m0 + w * 32 + i * 16 + lrow) * lda + kk + lk;
            const size_t boff = (size_t)(n0 + w * 32 + i * 16 + lrow) * ldb + kk + lk;
            const int ldst = (w * 32 + i * 16) * 32;
            gload16(Ah + aoff, &Ash[ldst]);
            gload16(Al + aoff, &Asl[ldst]);
            gload16(Bh + boff, &Bsh[ldst]);
            gload16(Bl + boff, &Bsl[ldst]);
        }
        __syncthreads();

        const int mi = lane & 15;
        const int ko = (lane >> 4) * 8;
        short8 ah[4], al[4], bh[4], bl[4];
        #pragma unroll
        for (int i = 0; i < 4; i++) {
            ah[i] = *(const short8*)&Ash[(wr + i * 16 + mi) * 32 + ko];
            al[i] = *(const short8*)&Asl[(wr + i * 16 + mi) * 32 + ko];
        }
        #pragma unroll
        for (int j = 0; j < 4; j++) {
            bh[j] = *(const short8*)&Bsh[(wc + j * 16 + mi) * 32 + ko];
            bl[j] = *(const short8*)&Bsl[(wc + j * 16 + mi) * 32 + ko];
        }
        #pragma unroll
        for (int i = 0; i < 4; i++)
            #pragma unroll
            for (int j = 0; j < 4; j++) {
                acc[i][j] = __builtin_amdgcn_mfma_f32_16x16x32_bf16(ah[i], bh[j], acc[i][j], 0, 0, 0);
                acc[i][j] = __builtin_amdgcn_mfma_f32_16x16x32_bf16(ah[i], bl[j], acc[i][j], 0, 0, 0);
                acc[i][j] = __builtin_amdgcn_mfma_f32_16x16x32_bf16(al[i], bh[j], acc[i][j], 0, 0, 0);
            }
        __syncthreads();
    }

    const int cr = (lane >> 4) * 4;
    const int cc = lane & 15;
    #pragma unroll
    for (int i = 0; i < 4; i++)
        #pragma unroll
        for (int j = 0; j < 4; j++) {
            const int gr = m0 + wr + i * 16 + cr;
            const int gc = n0 + wc + j * 16 + cc;
            #pragma unroll
            for (int r = 0; r < 4; r++)
                Ct[(size_t)gc * ldc + (gr + r)] = f2bf(acc[i][j][r]);
        }
}

// ---------------- encoder fast path: split-bf16 MFMA (fp32-grade precision) ----
// grid (4,128), XCD-swizzled.
__global__ __launch_bounds__(256)
void enc_gemm(const ushortT* __restrict__ Ah, const ushortT* __restrict__ Al,
              const ushortT* __restrict__ Bh, const ushortT* __restrict__ Bl,
              const float* __restrict__ bias, float* __restrict__ C)
{
    __shared__ ushortT Ash[128 * 32], Asl[128 * 32];
    __shared__ ushortT Bsh[128 * 32], Bsl[128 * 32];
    const int tid  = threadIdx.x;
    const int lane = tid & 63;
    const int w    = tid >> 6;
    const int wr   = (w >> 1) * 64;
    const int wc   = (w & 1) * 64;
    const int flat = blockIdx.x + (blockIdx.y << 2);       // nwg = 512
    const int swz  = (flat & 7) * 64 + (flat >> 3);
    const int n0   = (swz & 3) * 128;
    const int m0   = (swz >> 2) * 128;
    const int lrow = lane >> 2;
    const int lk   = (lane & 3) * 8;

    f32x4 acc[4][4];
    #pragma unroll
    for (int i = 0; i < 4; i++)
        #pragma unroll
        for (int j = 0; j < 4; j++) acc[i][j] = (f32x4){0.f, 0.f, 0.f, 0.f};

    for (int kk = 0; kk < DMODEL; kk += 32) {
        #pragma unroll
        for (int i = 0; i < 2; i++) {
            const size_t aoff = (size_t)(m0 + w * 32 + i * 16 + lrow) * DMODEL + kk + lk;
            const size_t boff = (size_t)(n0 + w * 32 + i * 16 + lrow) * DMODEL + kk + lk;
            const int ldst = (w * 32 + i * 16) * 32;
            gload16(Ah + aoff, &Ash[ldst]);
            gload16(Al + aoff, &Asl[ldst]);
            gload16(Bh + boff, &Bsh[ldst]);
            gload16(Bl + boff, &Bsl[ldst]);
        }
        __syncthreads();

        const int mi = lane & 15;
        const int ko = (lane >> 4) * 8;
        short8 ah[4], al[4], bh[4], bl[4];
        #pragma unroll
        for (int i = 0; i < 4; i++) {
            ah[i] = *(const short8*)&Ash[(wr + i * 16 + mi) * 32 + ko];
            al[i] = *(const short8*)&Asl[(wr + i * 16 + mi) * 32 + ko];
        }
        #pragma unroll
        for (int j = 0; j < 4; j++) {
            bh[j] = *(const short8*)&Bsh[(wc + j * 16 + mi) * 32 + ko];
            bl[j] = *(const short8*)&Bsl[(wc + j * 16 + mi) * 32 + ko];
        }
        #pragma unroll
        for (int i = 0; i < 4; i++)
            #pragma unroll
            for (int j = 0; j < 4; j++) {
                acc[i][j] = __builtin_amdgcn_mfma_f32_16x16x32_bf16(ah[i], bh[j], acc[i][j], 0, 0, 0);
                acc[i][j] = __builtin_amdgcn_mfma_f32_16x16x32_bf16(ah[i], bl[j], acc[i][j], 0, 0, 0);
                acc[i][j] = __builtin_amdgcn_mfma_f32_16x16x32_bf16(al[i], bh[j], acc[i][j], 0, 0, 0);
            }
        __syncthreads();
    }

    const int cr = (lane >> 4) * 4;
    const int cc = lane & 15;
    #pragma unroll
    for (int i = 0; i < 4; i++)
        #pragma unroll
        for (int j = 0; j < 4; j++) {
            const int gr = m0 + wr + i * 16 + cr;
            const int gc = n0 + wc + j * 16 + cc;
            #pragma unroll
            for (int r = 0; r < 4; r++)
                C[(size_t)(gr + r) * 512 + gc] = gelu_f(acc[i][j][r] + bias[gc]);
        }
}

// logit = gelu_row . W_re2 (fp64 accum of f32 values); flag borderline tokens
__global__ __launch_bounds__(256)
void target2_k(const float* __restrict__ Genc, const float* __restrict__ W2,
               const float* __restrict__ b2, float* __restrict__ outT,
               float* __restrict__ outS, int* __restrict__ gidx,
               int* __restrict__ cnt, int* __restrict__ list)
{
    const int m = blockIdx.x * 4 + (threadIdx.x >> 6);
    const int lane = threadIdx.x & 63;
    const float* gr = Genc + (size_t)m * 512;
    double s = 0.0;
    #pragma unroll 4
    for (int j = lane; j < 512; j += 64) s = fma((double)gr[j], (double)W2[j], s);
    #pragma unroll
    for (int off = 32; off; off >>= 1) s += __shfl_down(s, off);
    if (lane == 0) {
        double logit = s + (double)b2[0];
        double str = 1.0 / (1.0 + exp(-logit));
        double r = str * (double)(NSEQ - 1);
        double n = rint(r);
        double dist = fabs(r - n);             // distance to nearest integer
        n = fmin(fmax(n, 0.0), (double)(NSEQ - 1));
        int t = (int)n;
        outT[m] = (float)t;
        outS[m] = (float)str;
        gidx[m] = ((m >> 12) << 12) + t;
        if (dist > 0.46) {                      // within 0.04 of a .5 boundary
            int ix = atomicAdd(cnt, 1) & (MTOT - 1);   // defensive mask (list is 64KB)
            list[ix] = m;
        }
    }
}

// exact fp64 recompute for flagged tokens.
#define FIX_T 4
__global__ __launch_bounds__(256)
void fixup_k(const float* __restrict__ h, const float* __restrict__ W1,
             const float* __restrict__ b1, const float* __restrict__ W2,
             const float* __restrict__ b2, const int* __restrict__ cnt_p,
             const int* __restrict__ list, float* __restrict__ outT,
             float* __restrict__ outS, int* __restrict__ gidx)
{
    __shared__ float hrow[FIX_T][1024];
    __shared__ double red[4][FIX_T];
    const int tid = threadIdx.x;
    const int cnt = min(*cnt_p, MTOT);           // defensive clamp
    for (int base = (int)blockIdx.x * FIX_T; base < cnt;
         base += (int)gridDim.x * FIX_T) {
        const int nt = min(FIX_T, cnt - base);
        for (int t = 0; t < nt; t++) {
            const int m = list[base + t];
            const float4* src = (const float4*)(h + (size_t)m * 1024);
            ((float4*)hrow[t])[tid] = src[tid];   // 256 * 16B = 4 KB row
        }
        __syncthreads();

        double a[FIX_T][2];
        #pragma unroll
        for (int t = 0; t < FIX_T; t++) { a[t][0] = 0.0; a[t][1] = 0.0; }

        #pragma unroll 4
        for (int k = 0; k < 1024; k++) {
            const double wa = (double)W1[(size_t)k * 512 + tid];
            const double wb = (double)W1[(size_t)k * 512 + tid + 256];
            #pragma unroll
            for (int t = 0; t < FIX_T; t++) {
                const double hv = (double)hrow[t][k];
                a[t][0] = fma(hv, wa, a[t][0]);
                a[t][1] = fma(hv, wb, a[t][1]);
            }
        }

        const double w2a = (double)W2[tid], w2b = (double)W2[tid + 256];
        const double b1a = (double)b1[tid], b1b = (double)b1[tid + 256];
        const int lane = tid & 63, w = tid >> 6;
        #pragma unroll
        for (int t = 0; t < FIX_T; t++) {
            double v = w2a * gelu_d(a[t][0] + b1a) + w2b * gelu_d(a[t][1] + b1b);
            #pragma unroll
            for (int off = 32; off; off >>= 1) v += __shfl_down(v, off);
            if (lane == 0) red[w][t] = v;
        }
        __syncthreads();
        if (tid < nt) {
            const int t = tid;
            double logit = red[0][t] + red[1][t] + red[2][t] + red[3][t] + (double)b2[0];
            double str = 1.0 / (1.0 + exp(-logit));
            double r = str * (double)(NSEQ - 1);
            double n = rint(r);
            n = fmin(fmax(n, 0.0), (double)(NSEQ - 1));
            const int m = list[base + t];
            const int ti = (int)n;
            outT[m] = (float)ti;
            outS[m] = (float)str;
            gidx[m] = ((m >> 12) << 12) + ti;
        }
        __syncthreads();
    }
}

__global__ __launch_bounds__(256)
void biascomb_k(const float* __restrict__ brt2, const float* __restrict__ Wo,
                float* __restrict__ bc)
{
    int j = blockIdx.x * 256 + threadIdx.x;
    float s = 0.f;
    for (int e = 0; e < DMODEL; e++) s = fmaf(brt2[e], Wo[e * DMODEL + j], s);
    bc[j] = s;
}

// f32 -> bf16 straight cast
__global__ __launch_bounds__(256)
void cast_k(const float* __restrict__ x, ushortT* __restrict__ y, int n)
{
    int i = (blockIdx.x * 256 + threadIdx.x) * 4;
    if (i < n) {
        float4 v = *(const float4*)(x + i);
        ushortT o[4] = { f2bf(v.x), f2bf(v.y), f2bf(v.z), f2bf(v.w) };
        *(ulong1*)&y[i] = *(ulong1*)o;
    }
}

// f32 -> (hi bf16, lo bf16) 2-way split
__global__ __launch_bounds__(256)
void split_cast_k(const float* __restrict__ x, ushortT* __restrict__ yh,
                  ushortT* __restrict__ yl, int n)
{
    int i = (blockIdx.x * 256 + threadIdx.x) * 4;
    if (i < n) {
        float4 v = *(const float4*)(x + i);
        float vv[4] = { v.x, v.y, v.z, v.w };
        ushortT oh[4], ol[4];
        #pragma unroll
        for (int q = 0; q < 4; q++) {
            oh[q] = f2bf(vv[q]);
            ol[q] = f2bf(vv[q] - bf2f(oh[q]));
        }
        *(ulong1*)&yh[i] = *(ulong1*)oh;
        *(ulong1*)&yl[i] = *(ulong1*)ol;
    }
}

// W [K][N] f32 -> Wt [N][K] bf16
__global__ __launch_bounds__(256)
void transcast_k(const float* __restrict__ W, ushortT* __restrict__ Wt, int K, int N)
{
    __shared__ float t[32][33];
    const int tx = threadIdx.x & 31, ty = threadIdx.x >> 5;
    const int n0 = blockIdx.x * 32, k0 = blockIdx.y * 32;
    #pragma unroll
    for (int r = 0; r < 32; r += 8)
        t[ty + r][tx] = W[(size_t)(k0 + ty + r) * N + n0 + tx];
    __syncthreads();
    #pragma unroll
    for (int r = 0; r < 32; r += 8)
        Wt[(size_t)(n0 + ty + r) * K + k0 + tx] = f2bf(t[tx][ty + r]);
}

// W [K][N] f32 -> Wt_hi/lo [N][K] bf16 split
__global__ __launch_bounds__(256)
void split_transcast_k(const float* __restrict__ W, ushortT* __restrict__ Wth,
                       ushortT* __restrict__ Wtl, int K, int N)
{
    __shared__ float t[32][33];
    const int tx = threadIdx.x & 31, ty = threadIdx.x >> 5;
    const int n0 = blockIdx.x * 32, k0 = blockIdx.y * 32;
    #pragma unroll
    for (int r = 0; r < 32; r += 8)
        t[ty + r][tx] = W[(size_t)(k0 + ty + r) * N + n0 + tx];
    __syncthreads();
    #pragma unroll
    for (int r = 0; r < 32; r += 8) {
        float x = t[tx][ty + r];
        ushortT hi = f2bf(x);
        Wth[(size_t)(n0 + ty + r) * K + k0 + tx] = hi;
        Wtl[(size_t)(n0 + ty + r) * K + k0 + tx] = f2bf(x - bf2f(hi));
    }
}

extern "C" void kernel_launch(void* const* d_in, const int* in_sizes, int n_in,
                              void* d_out, int out_size, void* d_ws, size_t ws_size,
                              hipStream_t stream)
{
    const float* h     = (const float*)d_in[0];
    const float* W_re1 = (const float*)d_in[1];
    const float* b_re1 = (const float*)d_in[2];
    const float* W_re2 = (const float*)d_in[3];
    const float* b_re2 = (const float*)d_in[4];
    const float* W_v   = (const float*)d_in[5];
    const float* W_rt1 = (const float*)d_in[6];
    const float* b_rt1 = (const float*)d_in[7];
    const float* W_rt2 = (const float*)d_in[8];
    const float* b_rt2 = (const float*)d_in[9];
    const float* W_o   = (const float*)d_in[10];

    float* z    = (float*)d_out;                        // [16384,1024] f32
    float* outT = z + (size_t)MTOT * DMODEL;
    float* outS = outT + MTOT;
    ushortT* Q    = (ushortT*)z;                        // bf16 [16384,1024], lower 32 MB of z region
    ushortT* h_hi = (ushortT*)z + (size_t)MTOT * DMODEL;// bf16, upper 32 MB of z region

    char* ws = (char*)d_ws;
    ushortT* G       = (ushortT*)ws;                          // 32 MB  gelu(pre) bf16
    float*   Genc    = (float*)(ws + (32ull  << 20));         // 32 MB  encoder gelu f32 (freed after target2)
    ushortT* h_lo    = (ushortT*)(ws + (64ull  << 20));       // 32 MB  (freed after enc_gemm)
    float*   P       = (float*)(ws + (32ull  << 20));         // 64 MB  pre-act f32, REUSES Genc+h_lo region
    ushortT* Wrt1t_h = (ushortT*)(ws + (96ull  << 20));       // 4 MB  [1024][2048]
    ushortT* Wrt1t_l = (ushortT*)(ws + (100ull << 20));       // 4 MB
    ushortT* Wv_h    = (ushortT*)(ws + (104ull << 20));       // 2 MB  [1024][1024]
    ushortT* Wv_l    = (ushortT*)(ws + (106ull << 20));       // 2 MB
    ushortT* Wa_t    = (ushortT*)(ws + (108ull << 20));       // 4 MB  [Wa;Wb]^T bf16 [2048][1024]
    ushortT* Wo_t    = (ushortT*)(ws + (112ull << 20));       // 2 MB
    ushortT* Wrt2_b  = (ushortT*)(ws + (114ull << 20));       // 2 MB
    ushortT* Wc_t    = (ushortT*)(ws + (116ull << 20));       // 2 MB
    ushortT* Wre1t_h = (ushortT*)(ws + (118ull << 20));       // 1 MB [512][1024]
    ushortT* Wre1t_l = (ushortT*)(ws + (119ull << 20));       // 1 MB
    float*   b_c     = (float*)(ws + (120ull << 20));         // 4 KB
    int*     cnt     = (int*)  (ws + (120ull << 20) + 4096);  // 4 KB
    int*     gidx    = (int*)  (ws + (120ull << 20) + 8192);  // 64 KB
    int*     list    = (int*)  (ws + (120ull << 20) + 8192 + 65536); // 64 KB

    // --- casts / splits / transposes ---
    split_cast_k<<<dim3(MTOT * DMODEL / 1024), 256, 0, stream>>>(h, h_hi, h_lo, MTOT * DMODEL);
    split_cast_k<<<dim3(DMODEL * DMODEL / 1024), 256, 0, stream>>>(W_v, Wv_h, Wv_l, DMODEL * DMODEL);
    split_transcast_k<<<dim3(16, 32), 256, 0, stream>>>(W_re1, Wre1t_h, Wre1t_l, DMODEL, 512);
    split_transcast_k<<<dim3(32, 64), 256, 0, stream>>>(W_rt1, Wrt1t_h, Wrt1t_l, 2 * DMODEL, DMODEL);
    cast_k<<<dim3(DMODEL * DMODEL / 1024), 256, 0, stream>>>(W_rt2, Wrt2_b, DMODEL * DMODEL);
    transcast_k<<<dim3(32, 32), 256, 0, stream>>>(W_o, Wo_t, DMODEL, DMODEL);
    biascomb_k<<<dim3(4), 256, 0, stream>>>(b_rt2, W_o, b_c);

    // --- combined weights [Wa;Wb]^T in ONE launch (fp32-grade; 128 blocks) ---
    wsplit_gemm<<<dim3(8, 16), 256, 0, stream>>>(Wv_h, Wv_l, Wrt1t_h, Wrt1t_l,
                                                 Wa_t, DMODEL, DMODEL, 2 * DMODEL, DMODEL);

    // --- encoder fast path (split-bf16 MFMA, fp32-grade) ---
    enc_gemm<<<dim3(4, 128), 256, 0, stream>>>(h_hi, h_lo, Wre1t_h, Wre1t_l, b_re1, Genc);

    hipMemsetAsync(cnt, 0, 4, stream);
    target2_k<<<dim3(MTOT / 4), 256, 0, stream>>>(Genc, W_re2, b_re2, outT, outS, gidx, cnt, list);
    // exact fp64 recompute of borderline tokens (~8%)
    fixup_k<<<dim3(4096), 256, 0, stream>>>(h, W_re1, b_re1, W_re2, b_re2, cnt, list,
                                            outT, outS, gidx);

    // --- z path ---
    mfma_gemm<EPI_TRANS_BF16, 8><<<dim3(8, 8), 256, 0, stream>>>(
        Wrt2_b, Wo_t, nullptr, (void*)Wc_t, nullptr, DMODEL, DMODEL, DMODEL, DMODEL, 8);

    // [P|Q] = h @ [Wa;Wb]^T  — 256² 8-wave pipelined GEMM (counted vmcnt)
    pipe_gemm<EPI_PQ, 8><<<dim3(8, 64), 512, 0, stream>>>(
        h_hi, Wa_t, b_rt1, (void*)P, (void*)Q, DMODEL, DMODEL, DMODEL, DMODEL, 64);

    // G = bf16(gelu(P + Q[gidx]))  — row-granular coalesced gather
    gelu_gather_k<<<dim3(MTOT), 256, 0, stream>>>(P, Q, gidx, G);

    // z = G @ Wc + b_c  — pipelined GEMM
    pipe_gemm<EPI_BIAS_F32, 4><<<dim3(4, 64), 512, 0, stream>>>(
        G, Wc_t, b_c, (void*)z, nullptr, DMODEL, DMODEL, DMODEL, DMODEL, 32);
}

// Round 7
// 589.604 us; speedup vs baseline: 1.1924x; 1.0629x over previous
//
#include <hip/hip_runtime.h>
#include <math.h>
#include <type_traits>

#define DMODEL 1024
#define NSEQ   4096
#define MTOT   16384

typedef unsigned short ushortT;
typedef __attribute__((ext_vector_type(8))) short short8;
typedef __attribute__((ext_vector_type(4))) float f32x4;

__device__ __forceinline__ float gelu_f(float x) {
    return 0.5f * x * (1.0f + erff(x * 0.70710678118654752440f));
}
__device__ __forceinline__ double gelu_d(double x) {
    return 0.5 * x * (1.0 + erf(x * 0.70710678118654752440));
}
__device__ __forceinline__ ushortT f2bf(float f) {
    unsigned u = __float_as_uint(f);
    u += 0x7FFFu + ((u >> 16) & 1u);   // round-to-nearest-even
    return (ushortT)(u >> 16);
}
__device__ __forceinline__ float bf2f(ushortT b) {
    return __uint_as_float(((unsigned)b) << 16);
}
// async global->LDS, 16B per lane; LDS dest = wave-uniform base + lane*16
__device__ __forceinline__ void gload16(const void* g, void* l) {
    __builtin_amdgcn_global_load_lds(
        (const __attribute__((address_space(1))) unsigned*)g,
        (__attribute__((address_space(3))) unsigned*)l, 16, 0, 0);
}

enum { EPI_BIAS_F32 = 2, EPI_TRANS_BF16 = 3, EPI_PQ = 5 };

// T2 swizzle: row stride 128B = 8 slots of 16B; physical slot = logical ^ (row&7).
// Involution applied on BOTH the global source (staging) and the ds_read side;
// LDS dest of global_load_lds stays linear (rule #21). Returns ushort offset.
__device__ __forceinline__ int swz_off(int row, int slot) {
    return row * 64 + (((slot ^ (row & 7)) & 7) << 3);
}

// ---------------- 256x256 8-wave pipelined GEMM (T2+T3+T4+T5) ----------------
// C = epi(A @ Bt^T [+bias]); A [M,K] bf16 (lda), Bt [N,K] bf16 (ldb). K%64==0.
// 512 thr = 8 waves (2M x 4N); BK=64; LDS 128 KiB double-buffered.
// Counted vmcnt(2) once per K-tile keeps next-tile loads in flight across
// barriers; raw s_barrier (no implicit vmcnt(0) drain). XOR slot swizzle kills
// the 16-way ds_read_b128 bank conflict of the linear layout (r6: 18.9M).
// Accumulation order per fragment identical to m97 -> bit-identical results.
template<int EPI, int NXT>
__global__ __launch_bounds__(512, 2)
void pipe_gemm(const ushortT* __restrict__ A, const ushortT* __restrict__ Bt,
               const float* __restrict__ bias, void* __restrict__ Cv,
               void* __restrict__ Cv2, int K, int lda, int ldb, int ldc, int cpx)
{
    // [A0 | A1 | B0 | B1], each 256*64 bf16 = 32 KiB
    __shared__ ushortT smem[4 * 16384];
    const int tid  = threadIdx.x;            // 0..511
    const int lane = tid & 63;
    const int w    = tid >> 6;               // 0..7
    const int wr   = w >> 2;                 // 0..1 : M half (128 rows)
    const int wc   = w & 3;                  // 0..3 : N quarter (64 cols)
    const int flat = blockIdx.x + blockIdx.y * NXT;
    const int swz  = (flat & 7) * cpx + (flat >> 3);   // XCD swizzle (nwg%8==0)
    const int n0   = (swz & (NXT - 1)) * 256;
    const int m0   = (swz / NXT) * 256;

    // staging map: issue q covers tile rows [q*64, q*64+64); thread -> row tid/8.
    // Global col is PRE-SWIZZLED: LDS physical slot (lane&7) of row srow receives
    // logical slot (lane&7)^(srow&7).  LDS dest stays linear (base + lane*16).
    const int srow  = tid >> 3;
    const int sscol = (((tid & 7) ^ (srow & 7)) & 7) << 3;   // elements

#define STG_A(buf, q, k0) gload16(A  + (size_t)(m0 + (q)*64 + srow) * lda + (k0) + sscol, \
                                  (char*)smem + (buf)*32768 + (q)*8192 + w*1024)
#define STG_B(buf, q, k0) gload16(Bt + (size_t)(n0 + (q)*64 + srow) * ldb + (k0) + sscol, \
                                  (char*)smem + 65536 + (buf)*32768 + (q)*8192 + w*1024)
#define BAR() asm volatile("s_barrier" ::: "memory")

    f32x4 acc[8][4];
    #pragma unroll
    for (int i = 0; i < 8; i++)
        #pragma unroll
        for (int j = 0; j < 4; j++) acc[i][j] = (f32x4){0.f, 0.f, 0.f, 0.f};

    const int NT = K >> 6;                   // K-tiles of 64

    // prologue: stage tile 0 into buf 0 (8 loads/wave)
    #pragma unroll
    for (int q = 0; q < 4; q++) { STG_A(0, q, 0); STG_B(0, q, 0); }

    const int mi = lane & 15;
    const int g4 = lane >> 4;                // 0..3 : k-slot sub-index

    for (int t = 0; t < NT; ++t) {
        const int c  = t & 1;
        const int nb = c ^ 1;
        const int kn = (t + 1) << 6;
        const bool hn = (t + 1 < NT);

        // ---- phase 0: stage 2, counted wait, sync, B frags + A quad 0 ----
        if (hn) {
            STG_A(nb, 0, kn); STG_A(nb, 1, kn);
            asm volatile("s_waitcnt vmcnt(2)" ::: "memory");  // tile t fully landed
        } else {
            asm volatile("s_waitcnt vmcnt(0)" ::: "memory");
        }
        BAR();

        short8 bf[4][2];
        #pragma unroll
        for (int nf = 0; nf < 4; nf++)
            #pragma unroll
            for (int ks = 0; ks < 2; ks++)
                bf[nf][ks] = *(const short8*)&smem[32768 + c * 16384 +
                                swz_off(wc * 64 + nf * 16 + mi, ks * 4 + g4)];

        #pragma unroll
        for (int p = 0; p < 4; p++) {
            if (p > 0) {
                if (hn) {
                    if (p == 1) { STG_A(nb, 2, kn); STG_A(nb, 3, kn); }
                    if (p == 2) { STG_B(nb, 0, kn); STG_B(nb, 1, kn); }
                    if (p == 3) { STG_B(nb, 2, kn); STG_B(nb, 3, kn); }
                }
                BAR();
            }
            short8 af[2][2];
            #pragma unroll
            for (int ii = 0; ii < 2; ii++)
                #pragma unroll
                for (int ks = 0; ks < 2; ks++)
                    af[ii][ks] = *(const short8*)&smem[c * 16384 +
                                    swz_off(wr * 128 + (p * 2 + ii) * 16 + mi, ks * 4 + g4)];
            __builtin_amdgcn_s_setprio(1);
            #pragma unroll
            for (int ks = 0; ks < 2; ks++)
                #pragma unroll
                for (int ii = 0; ii < 2; ii++)
                    #pragma unroll
                    for (int nf = 0; nf < 4; nf++)
                        acc[p * 2 + ii][nf] = __builtin_amdgcn_mfma_f32_16x16x32_bf16(
                            af[ii][ks], bf[nf][ks], acc[p * 2 + ii][nf], 0, 0, 0);
            __builtin_amdgcn_s_setprio(0);
        }
        BAR();   // all reads of buf c done before next iter's stage overwrites it
    }

    const int cr = (lane >> 4) * 4;
    #pragma unroll
    for (int i = 0; i < 8; i++) {
        #pragma unroll
        for (int j = 0; j < 4; j++) {
            const int gr = m0 + wr * 128 + i * 16 + cr;
            const int gc = n0 + wc * 64 + j * 16 + mi;
            #pragma unroll
            for (int r = 0; r < 4; r++) {
                float v = acc[i][j][r];
                if constexpr (EPI == EPI_BIAS_F32) {
                    ((float*)Cv)[(size_t)(gr + r) * ldc + gc] = v + bias[gc];
                } else {   // EPI_PQ: cols <1024 -> P (f32+bias), else -> Q (bf16)
                    if (gc < 1024)
                        ((float*)Cv)[(size_t)(gr + r) * ldc + gc] = v + bias[gc];
                    else
                        ((ushortT*)Cv2)[(size_t)(gr + r) * ldc + (gc - 1024)] = f2bf(v);
                }
            }
        }
    }
#undef STG_A
#undef STG_B
#undef BAR
}

// ---------------- bf16 MFMA GEMM (m97 structure, XCD-swizzled) ----------------
// Retained for the small Wc_t transpose GEMM.
template<int EPI, int NXT>
__global__ __launch_bounds__(256)
void mfma_gemm(const ushortT* __restrict__ A, const ushortT* __restrict__ Bt,
               const float* __restrict__ bias, void* __restrict__ Cv,
               void* __restrict__ Cv2, int K, int lda, int ldb, int ldc, int cpx)
{
    __shared__ ushortT As[128 * 32];
    __shared__ ushortT Bs[128 * 32];
    const int tid  = threadIdx.x;
    const int lane = tid & 63;
    const int w    = tid >> 6;
    const int wr   = (w >> 1) * 64;
    const int wc   = (w & 1) * 64;
    const int flat = blockIdx.x + blockIdx.y * NXT;
    const int swz  = (flat & 7) * cpx + (flat >> 3);
    const int n0   = (swz & (NXT - 1)) * 128;
    const int m0   = (swz / NXT) * 128;

    const int lrow = lane >> 2;
    const int lk   = (lane & 3) * 8;

    f32x4 acc[4][4];
    #pragma unroll
    for (int i = 0; i < 4; i++)
        #pragma unroll
        for (int j = 0; j < 4; j++) acc[i][j] = (f32x4){0.f, 0.f, 0.f, 0.f};

    for (int kk = 0; kk < K; kk += 32) {
        #pragma unroll
        for (int i = 0; i < 2; i++) {
            const ushortT* ga = A + (size_t)(m0 + w * 32 + i * 16 + lrow) * lda + kk + lk;
            gload16(ga, &As[(w * 32 + i * 16) * 32]);
            const ushortT* gb = Bt + (size_t)(n0 + w * 32 + i * 16 + lrow) * ldb + kk + lk;
            gload16(gb, &Bs[(w * 32 + i * 16) * 32]);
        }
        __syncthreads();

        const int mi = lane & 15;
        const int ko = (lane >> 4) * 8;
        short8 a[4], b[4];
        #pragma unroll
        for (int i = 0; i < 4; i++)
            a[i] = *(const short8*)&As[(wr + i * 16 + mi) * 32 + ko];
        #pragma unroll
        for (int j = 0; j < 4; j++)
            b[j] = *(const short8*)&Bs[(wc + j * 16 + mi) * 32 + ko];
        #pragma unroll
        for (int i = 0; i < 4; i++)
            #pragma unroll
            for (int j = 0; j < 4; j++)
                acc[i][j] = __builtin_amdgcn_mfma_f32_16x16x32_bf16(a[i], b[j], acc[i][j], 0, 0, 0);
        __syncthreads();
    }

    const int cr = (lane >> 4) * 4;
    const int cc = lane & 15;
    #pragma unroll
    for (int i = 0; i < 4; i++) {
        #pragma unroll
        for (int j = 0; j < 4; j++) {
            const int gr = m0 + wr + i * 16 + cr;
            const int gc = n0 + wc + j * 16 + cc;
            #pragma unroll
            for (int r = 0; r < 4; r++) {
                float v = acc[i][j][r];
                if constexpr (EPI == EPI_BIAS_F32)
                    ((float*)Cv)[(size_t)(gr + r) * ldc + gc] = v + bias[gc];
                else
                    ((ushortT*)Cv)[(size_t)gc * ldc + (gr + r)] = f2bf(v);
            }
        }
    }
}

// ---------------- row-granular gather + gelu:  G[m] = bf16(gelu(P[m] + Q[gidx[m]])) ----
__global__ __launch_bounds__(256)
void gelu_gather_k(const float* __restrict__ P, const ushortT* __restrict__ Q,
                   const int* __restrict__ gidx, ushortT* __restrict__ G)
{
    const int m = blockIdx.x;
    int t = gidx[m];                             // wave-uniform per block
    t = max(0, min(t, MTOT - 1));                // defensive clamp (poison-proof)
    const int c = threadIdx.x * 4;
    float4 p = *(const float4*)(P + (size_t)m * DMODEL + c);
    ushort4 q = *(const ushort4*)(Q + (size_t)t * DMODEL + c);
    ushortT o[4];
    o[0] = f2bf(gelu_f(p.x + bf2f(q.x)));
    o[1] = f2bf(gelu_f(p.y + bf2f(q.y)));
    o[2] = f2bf(gelu_f(p.z + bf2f(q.z)));
    o[3] = f2bf(gelu_f(p.w + bf2f(q.w)));
    *(ulong1*)(G + (size_t)m * DMODEL + c) = *(ulong1*)o;
}

// ---------------- fp32-grade split-bf16 GEMM, transposed bf16 out ----------
// Combined launch: grid (8,16); blockIdx.y>=8 selects the Wb half (K-offset +1024).
__global__ __launch_bounds__(256)
void wsplit_gemm(const ushortT* __restrict__ Ah, const ushortT* __restrict__ Al,
                 const ushortT* __restrict__ Bh0, const ushortT* __restrict__ Bl0,
                 ushortT* __restrict__ Ct0, int K, int lda, int ldb, int ldc)
{
    __shared__ ushortT Ash[128 * 32], Asl[128 * 32];
    __shared__ ushortT Bsh[128 * 32], Bsl[128 * 32];
    const int tid  = threadIdx.x;
    const int lane = tid & 63;
    const int w    = tid >> 6;
    const int wr   = (w >> 1) * 64;
    const int wc   = (w & 1) * 64;
    const int sel  = blockIdx.y >> 3;
    const int m0   = (blockIdx.y & 7) * 128;
    const int n0   = blockIdx.x * 128;
    const ushortT* Bh = Bh0 + sel * 1024;        // K-offset into Wrt1t (ldb = 2048)
    const ushortT* Bl = Bl0 + sel * 1024;
    ushortT* Ct = Ct0 + (size_t)sel * 1024 * 1024;
    const int lrow = lane >> 2;
    const int lk   = (lane & 3) * 8;

    f32x4 acc[4][4];
    #pragma unroll
    for (int i = 0; i < 4; i++)
        #pragma unroll
        for (int j = 0; j < 4; j++) acc[i][j] = (f32x4){0.f, 0.f, 0.f, 0.f};

    for (int kk = 0; kk < K; kk += 32) {
        #pragma unroll
        for (int i = 0; i < 2; i++) {
            const size_t aoff = (size_t)(m0 + w * 32 + i * 16 + lrow) * lda + kk + lk;
            const size_t boff = (size_t)(n0 + w * 32 + i * 16 + lrow) * ldb + kk + lk;
            const int ldst = (w * 32 + i * 16) * 32;
            gload16(Ah + aoff, &Ash[ldst]);
            gload16(Al + aoff, &Asl[ldst]);
            gload16(Bh + boff, &Bsh[ldst]);
            gload16(Bl + boff, &Bsl[ldst]);
        }
        __syncthreads();

        const int mi = lane & 15;
        const int ko = (lane >> 4) * 8;
        short8 ah[4], al[4], bh[4], bl[4];
        #pragma unroll
        for (int i = 0; i < 4; i++) {
            ah[i] = *(const short8*)&Ash[(wr + i * 16 + mi) * 32 + ko];
            al[i] = *(const short8*)&Asl[(wr + i * 16 + mi) * 32 + ko];
        }
        #pragma unroll
        for (int j = 0; j < 4; j++) {
            bh[j] = *(const short8*)&Bsh[(wc + j * 16 + mi) * 32 + ko];
            bl[j] = *(const short8*)&Bsl[(wc + j * 16 + mi) * 32 + ko];
        }
        #pragma unroll
        for (int i = 0; i < 4; i++)
            #pragma unroll
            for (int j = 0; j < 4; j++) {
                acc[i][j] = __builtin_amdgcn_mfma_f32_16x16x32_bf16(ah[i], bh[j], acc[i][j], 0, 0, 0);
                acc[i][j] = __builtin_amdgcn_mfma_f32_16x16x32_bf16(ah[i], bl[j], acc[i][j], 0, 0, 0);
                acc[i][j] = __builtin_amdgcn_mfma_f32_16x16x32_bf16(al[i], bh[j], acc[i][j], 0, 0, 0);
            }
        __syncthreads();
    }

    const int cr = (lane >> 4) * 4;
    const int cc = lane & 15;
    #pragma unroll
    for (int i = 0; i < 4; i++)
        #pragma unroll
        for (int j = 0; j < 4; j++) {
            const int gr = m0 + wr + i * 16 + cr;
            const int gc = n0 + wc + j * 16 + cc;
            #pragma unroll
            for (int r = 0; r < 4; r++)
                Ct[(size_t)gc * ldc + (gr + r)] = f2bf(acc[i][j][r]);
        }
}

// ---------------- encoder fast path: split-bf16 MFMA (fp32-grade precision) ----
// grid (4,128), XCD-swizzled.
__global__ __launch_bounds__(256)
void enc_gemm(const ushortT* __restrict__ Ah, const ushortT* __restrict__ Al,
              const ushortT* __restrict__ Bh, const ushortT* __restrict__ Bl,
              const float* __restrict__ bias, float* __restrict__ C)
{
    __shared__ ushortT Ash[128 * 32], Asl[128 * 32];
    __shared__ ushortT Bsh[128 * 32], Bsl[128 * 32];
    const int tid  = threadIdx.x;
    const int lane = tid & 63;
    const int w    = tid >> 6;
    const int wr   = (w >> 1) * 64;
    const int wc   = (w & 1) * 64;
    const int flat = blockIdx.x + (blockIdx.y << 2);       // nwg = 512
    const int swz  = (flat & 7) * 64 + (flat >> 3);
    const int n0   = (swz & 3) * 128;
    const int m0   = (swz >> 2) * 128;
    const int lrow = lane >> 2;
    const int lk   = (lane & 3) * 8;

    f32x4 acc[4][4];
    #pragma unroll
    for (int i = 0; i < 4; i++)
        #pragma unroll
        for (int j = 0; j < 4; j++) acc[i][j] = (f32x4){0.f, 0.f, 0.f, 0.f};

    for (int kk = 0; kk < DMODEL; kk += 32) {
        #pragma unroll
        for (int i = 0; i < 2; i++) {
            const size_t aoff = (size_t)(m0 + w * 32 + i * 16 + lrow) * DMODEL + kk + lk;
            const size_t boff = (size_t)(n0 + w * 32 + i * 16 + lrow) * DMODEL + kk + lk;
            const int ldst = (w * 32 + i * 16) * 32;
            gload16(Ah + aoff, &Ash[ldst]);
            gload16(Al + aoff, &Asl[ldst]);
            gload16(Bh + boff, &Bsh[ldst]);
            gload16(Bl + boff, &Bsl[ldst]);
        }
        __syncthreads();

        const int mi = lane & 15;
        const int ko = (lane >> 4) * 8;
        short8 ah[4], al[4], bh[4], bl[4];
        #pragma unroll
        for (int i = 0; i < 4; i++) {
            ah[i] = *(const short8*)&Ash[(wr + i * 16 + mi) * 32 + ko];
            al[i] = *(const short8*)&Asl[(wr + i * 16 + mi) * 32 + ko];
        }
        #pragma unroll
        for (int j = 0; j < 4; j++) {
            bh[j] = *(const short8*)&Bsh[(wc + j * 16 + mi) * 32 + ko];
            bl[j] = *(const short8*)&Bsl[(wc + j * 16 + mi) * 32 + ko];
        }
        #pragma unroll
        for (int i = 0; i < 4; i++)
            #pragma unroll
            for (int j = 0; j < 4; j++) {
                acc[i][j] = __builtin_amdgcn_mfma_f32_16x16x32_bf16(ah[i], bh[j], acc[i][j], 0, 0, 0);
                acc[i][j] = __builtin_amdgcn_mfma_f32_16x16x32_bf16(ah[i], bl[j], acc[i][j], 0, 0, 0);
                acc[i][j] = __builtin_amdgcn_mfma_f32_16x16x32_bf16(al[i], bh[j], acc[i][j], 0, 0, 0);
            }
        __syncthreads();
    }

    const int cr = (lane >> 4) * 4;
    const int cc = lane & 15;
    #pragma unroll
    for (int i = 0; i < 4; i++)
        #pragma unroll
        for (int j = 0; j < 4; j++) {
            const int gr = m0 + wr + i * 16 + cr;
            const int gc = n0 + wc + j * 16 + cc;
            #pragma unroll
            for (int r = 0; r < 4; r++)
                C[(size_t)(gr + r) * 512 + gc] = gelu_f(acc[i][j][r] + bias[gc]);
        }
}

// logit = gelu_row . W_re2 (fp64 accum of f32 values); flag borderline tokens
__global__ __launch_bounds__(256)
void target2_k(const float* __restrict__ Genc, const float* __restrict__ W2,
               const float* __restrict__ b2, float* __restrict__ outT,
               float* __restrict__ outS, int* __restrict__ gidx,
               int* __restrict__ cnt, int* __restrict__ list)
{
    const int m = blockIdx.x * 4 + (threadIdx.x >> 6);
    const int lane = threadIdx.x & 63;
    const float* gr = Genc + (size_t)m * 512;
    double s = 0.0;
    #pragma unroll 4
    for (int j = lane; j < 512; j += 64) s = fma((double)gr[j], (double)W2[j], s);
    #pragma unroll
    for (int off = 32; off; off >>= 1) s += __shfl_down(s, off);
    if (lane == 0) {
        double logit = s + (double)b2[0];
        double str = 1.0 / (1.0 + exp(-logit));
        double r = str * (double)(NSEQ - 1);
        double n = rint(r);
        double dist = fabs(r - n);             // distance to nearest integer
        n = fmin(fmax(n, 0.0), (double)(NSEQ - 1));
        int t = (int)n;
        outT[m] = (float)t;
        outS[m] = (float)str;
        gidx[m] = ((m >> 12) << 12) + t;
        if (dist > 0.46) {                      // within 0.04 of a .5 boundary
            int ix = atomicAdd(cnt, 1) & (MTOT - 1);   // defensive mask (list is 64KB)
            list[ix] = m;
        }
    }
}

// exact fp64 recompute for flagged tokens.
#define FIX_T 4
__global__ __launch_bounds__(256)
void fixup_k(const float* __restrict__ h, const float* __restrict__ W1,
             const float* __restrict__ b1, const float* __restrict__ W2,
             const float* __restrict__ b2, const int* __restrict__ cnt_p,
             const int* __restrict__ list, float* __restrict__ outT,
             float* __restrict__ outS, int* __restrict__ gidx)
{
    __shared__ float hrow[FIX_T][1024];
    __shared__ double red[4][FIX_T];
    const int tid = threadIdx.x;
    const int cnt = min(*cnt_p, MTOT);           // defensive clamp
    for (int base = (int)blockIdx.x * FIX_T; base < cnt;
         base += (int)gridDim.x * FIX_T) {
        const int nt = min(FIX_T, cnt - base);
        for (int t = 0; t < nt; t++) {
            const int m = list[base + t];
            const float4* src = (const float4*)(h + (size_t)m * 1024);
            ((float4*)hrow[t])[tid] = src[tid];   // 256 * 16B = 4 KB row
        }
        __syncthreads();

        double a[FIX_T][2];
        #pragma unroll
        for (int t = 0; t < FIX_T; t++) { a[t][0] = 0.0; a[t][1] = 0.0; }

        #pragma unroll 4
        for (int k = 0; k < 1024; k++) {
            const double wa = (double)W1[(size_t)k * 512 + tid];
            const double wb = (double)W1[(size_t)k * 512 + tid + 256];
            #pragma unroll
            for (int t = 0; t < FIX_T; t++) {
                const double hv = (double)hrow[t][k];
                a[t][0] = fma(hv, wa, a[t][0]);
                a[t][1] = fma(hv, wb, a[t][1]);
            }
        }

        const double w2a = (double)W2[tid], w2b = (double)W2[tid + 256];
        const double b1a = (double)b1[tid], b1b = (double)b1[tid + 256];
        const int lane = tid & 63, w = tid >> 6;
        #pragma unroll
        for (int t = 0; t < FIX_T; t++) {
            double v = w2a * gelu_d(a[t][0] + b1a) + w2b * gelu_d(a[t][1] + b1b);
            #pragma unroll
            for (int off = 32; off; off >>= 1) v += __shfl_down(v, off);
            if (lane == 0) red[w][t] = v;
        }
        __syncthreads();
        if (tid < nt) {
            const int t = tid;
            double logit = red[0][t] + red[1][t] + red[2][t] + red[3][t] + (double)b2[0];
            double str = 1.0 / (1.0 + exp(-logit));
            double r = str * (double)(NSEQ - 1);
            double n = rint(r);
            n = fmin(fmax(n, 0.0), (double)(NSEQ - 1));
            const int m = list[base + t];
            const int ti = (int)n;
            outT[m] = (float)ti;
            outS[m] = (float)str;
            gidx[m] = ((m >> 12) << 12) + ti;
        }
        __syncthreads();
    }
}

__global__ __launch_bounds__(256)
void biascomb_k(const float* __restrict__ brt2, const float* __restrict__ Wo,
                float* __restrict__ bc)
{
    int j = blockIdx.x * 256 + threadIdx.x;
    float s = 0.f;
    for (int e = 0; e < DMODEL; e++) s = fmaf(brt2[e], Wo[e * DMODEL + j], s);
    bc[j] = s;
}

// f32 -> bf16 straight cast
__global__ __launch_bounds__(256)
void cast_k(const float* __restrict__ x, ushortT* __restrict__ y, int n)
{
    int i = (blockIdx.x * 256 + threadIdx.x) * 4;
    if (i < n) {
        float4 v = *(const float4*)(x + i);
        ushortT o[4] = { f2bf(v.x), f2bf(v.y), f2bf(v.z), f2bf(v.w) };
        *(ulong1*)&y[i] = *(ulong1*)o;
    }
}

// f32 -> (hi bf16, lo bf16) 2-way split
__global__ __launch_bounds__(256)
void split_cast_k(const float* __restrict__ x, ushortT* __restrict__ yh,
                  ushortT* __restrict__ yl, int n)
{
    int i = (blockIdx.x * 256 + threadIdx.x) * 4;
    if (i < n) {
        float4 v = *(const float4*)(x + i);
        float vv[4] = { v.x, v.y, v.z, v.w };
        ushortT oh[4], ol[4];
        #pragma unroll
        for (int q = 0; q < 4; q++) {
            oh[q] = f2bf(vv[q]);
            ol[q] = f2bf(vv[q] - bf2f(oh[q]));
        }
        *(ulong1*)&yh[i] = *(ulong1*)oh;
        *(ulong1*)&yl[i] = *(ulong1*)ol;
    }
}

// W [K][N] f32 -> Wt [N][K] bf16
__global__ __launch_bounds__(256)
void transcast_k(const float* __restrict__ W, ushortT* __restrict__ Wt, int K, int N)
{
    __shared__ float t[32][33];
    const int tx = threadIdx.x & 31, ty = threadIdx.x >> 5;
    const int n0 = blockIdx.x * 32, k0 = blockIdx.y * 32;
    #pragma unroll
    for (int r = 0; r < 32; r += 8)
        t[ty + r][tx] = W[(size_t)(k0 + ty + r) * N + n0 + tx];
    __syncthreads();
    #pragma unroll
    for (int r = 0; r < 32; r += 8)
        Wt[(size_t)(n0 + ty + r) * K + k0 + tx] = f2bf(t[tx][ty + r]);
}

// W [K][N] f32 -> Wt_hi/lo [N][K] bf16 split
__global__ __launch_bounds__(256)
void split_transcast_k(const float* __restrict__ W, ushortT* __restrict__ Wth,
                       ushortT* __restrict__ Wtl, int K, int N)
{
    __shared__ float t[32][33];
    const int tx = threadIdx.x & 31, ty = threadIdx.x >> 5;
    const int n0 = blockIdx.x * 32, k0 = blockIdx.y * 32;
    #pragma unroll
    for (int r = 0; r < 32; r += 8)
        t[ty + r][tx] = W[(size_t)(k0 + ty + r) * N + n0 + tx];
    __syncthreads();
    #pragma unroll
    for (int r = 0; r < 32; r += 8) {
        float x = t[tx][ty + r];
        ushortT hi = f2bf(x);
        Wth[(size_t)(n0 + ty + r) * K + k0 + tx] = hi;
        Wtl[(size_t)(n0 + ty + r) * K + k0 + tx] = f2bf(x - bf2f(hi));
    }
}

extern "C" void kernel_launch(void* const* d_in, const int* in_sizes, int n_in,
                              void* d_out, int out_size, void* d_ws, size_t ws_size,
                              hipStream_t stream)
{
    const float* h     = (const float*)d_in[0];
    const float* W_re1 = (const float*)d_in[1];
    const float* b_re1 = (const float*)d_in[2];
    const float* W_re2 = (const float*)d_in[3];
    const float* b_re2 = (const float*)d_in[4];
    const float* W_v   = (const float*)d_in[5];
    const float* W_rt1 = (const float*)d_in[6];
    const float* b_rt1 = (const float*)d_in[7];
    const float* W_rt2 = (const float*)d_in[8];
    const float* b_rt2 = (const float*)d_in[9];
    const float* W_o   = (const float*)d_in[10];

    float* z    = (float*)d_out;                        // [16384,1024] f32
    float* outT = z + (size_t)MTOT * DMODEL;
    float* outS = outT + MTOT;
    ushortT* Q    = (ushortT*)z;                        // bf16 [16384,1024], lower 32 MB of z region
    ushortT* h_hi = (ushortT*)z + (size_t)MTOT * DMODEL;// bf16, upper 32 MB of z region

    char* ws = (char*)d_ws;
    ushortT* G       = (ushortT*)ws;                          // 32 MB  gelu(pre) bf16
    float*   Genc    = (float*)(ws + (32ull  << 20));         // 32 MB  encoder gelu f32 (freed after target2)
    ushortT* h_lo    = (ushortT*)(ws + (64ull  << 20));       // 32 MB  (freed after enc_gemm)
    float*   P       = (float*)(ws + (32ull  << 20));         // 64 MB  pre-act f32, REUSES Genc+h_lo region
    ushortT* Wrt1t_h = (ushortT*)(ws + (96ull  << 20));       // 4 MB  [1024][2048]
    ushortT* Wrt1t_l = (ushortT*)(ws + (100ull << 20));       // 4 MB
    ushortT* Wv_h    = (ushortT*)(ws + (104ull << 20));       // 2 MB  [1024][1024]
    ushortT* Wv_l    = (ushortT*)(ws + (106ull << 20));       // 2 MB
    ushortT* Wa_t    = (ushortT*)(ws + (108ull << 20));       // 4 MB  [Wa;Wb]^T bf16 [2048][1024]
    ushortT* Wo_t    = (ushortT*)(ws + (112ull << 20));       // 2 MB
    ushortT* Wrt2_b  = (ushortT*)(ws + (114ull << 20));       // 2 MB
    ushortT* Wc_t    = (ushortT*)(ws + (116ull << 20));       // 2 MB
    ushortT* Wre1t_h = (ushortT*)(ws + (118ull << 20));       // 1 MB [512][1024]
    ushortT* Wre1t_l = (ushortT*)(ws + (119ull << 20));       // 1 MB
    float*   b_c     = (float*)(ws + (120ull << 20));         // 4 KB
    int*     cnt     = (int*)  (ws + (120ull << 20) + 4096);  // 4 KB
    int*     gidx    = (int*)  (ws + (120ull << 20) + 8192);  // 64 KB
    int*     list    = (int*)  (ws + (120ull << 20) + 8192 + 65536); // 64 KB

    // --- casts / splits / transposes ---
    split_cast_k<<<dim3(MTOT * DMODEL / 1024), 256, 0, stream>>>(h, h_hi, h_lo, MTOT * DMODEL);
    split_cast_k<<<dim3(DMODEL * DMODEL / 1024), 256, 0, stream>>>(W_v, Wv_h, Wv_l, DMODEL * DMODEL);
    split_transcast_k<<<dim3(16, 32), 256, 0, stream>>>(W_re1, Wre1t_h, Wre1t_l, DMODEL, 512);
    split_transcast_k<<<dim3(32, 64), 256, 0, stream>>>(W_rt1, Wrt1t_h, Wrt1t_l, 2 * DMODEL, DMODEL);
    cast_k<<<dim3(DMODEL * DMODEL / 1024), 256, 0, stream>>>(W_rt2, Wrt2_b, DMODEL * DMODEL);
    transcast_k<<<dim3(32, 32), 256, 0, stream>>>(W_o, Wo_t, DMODEL, DMODEL);
    biascomb_k<<<dim3(4), 256, 0, stream>>>(b_rt2, W_o, b_c);

    // --- combined weights [Wa;Wb]^T in ONE launch (fp32-grade; 128 blocks) ---
    wsplit_gemm<<<dim3(8, 16), 256, 0, stream>>>(Wv_h, Wv_l, Wrt1t_h, Wrt1t_l,
                                                 Wa_t, DMODEL, DMODEL, 2 * DMODEL, DMODEL);

    // --- encoder fast path (split-bf16 MFMA, fp32-grade) ---
    enc_gemm<<<dim3(4, 128), 256, 0, stream>>>(h_hi, h_lo, Wre1t_h, Wre1t_l, b_re1, Genc);

    hipMemsetAsync(cnt, 0, 4, stream);
    target2_k<<<dim3(MTOT / 4), 256, 0, stream>>>(Genc, W_re2, b_re2, outT, outS, gidx, cnt, list);
    // exact fp64 recompute of borderline tokens (~8%)
    fixup_k<<<dim3(4096), 256, 0, stream>>>(h, W_re1, b_re1, W_re2, b_re2, cnt, list,
                                            outT, outS, gidx);

    // --- z path ---
    mfma_gemm<EPI_TRANS_BF16, 8><<<dim3(8, 8), 256, 0, stream>>>(
        Wrt2_b, Wo_t, nullptr, (void*)Wc_t, nullptr, DMODEL, DMODEL, DMODEL, DMODEL, 8);

    // [P|Q] = h @ [Wa;Wb]^T  — 256² 8-wave pipelined GEMM (counted vmcnt + T2 swizzle)
    pipe_gemm<EPI_PQ, 8><<<dim3(8, 64), 512, 0, stream>>>(
        h_hi, Wa_t, b_rt1, (void*)P, (void*)Q, DMODEL, DMODEL, DMODEL, DMODEL, 64);

    // G = bf16(gelu(P + Q[gidx]))  — row-granular coalesced gather
    gelu_gather_k<<<dim3(MTOT), 256, 0, stream>>>(P, Q, gidx, G);

    // z = G @ Wc + b_c  — pipelined GEMM
    pipe_gemm<EPI_BIAS_F32, 4><<<dim3(4, 64), 512, 0, stream>>>(
        G, Wc_t, b_c, (void*)z, nullptr, DMODEL, DMODEL, DMODEL, DMODEL, 32);
}

// Round 8
// 583.984 us; speedup vs baseline: 1.2038x; 1.0096x over previous
//
#include <hip/hip_runtime.h>
#include <math.h>
#include <type_traits>

#define DMODEL 1024
#define NSEQ   4096
#define MTOT   16384

typedef unsigned short ushortT;
typedef __attribute__((ext_vector_type(8))) short short8;
typedef __attribute__((ext_vector_type(4))) float f32x4;

__device__ __forceinline__ float gelu_f(float x) {
    return 0.5f * x * (1.0f + erff(x * 0.70710678118654752440f));
}
__device__ __forceinline__ double gelu_d(double x) {
    return 0.5 * x * (1.0 + erf(x * 0.70710678118654752440));
}
__device__ __forceinline__ ushortT f2bf(float f) {
    unsigned u = __float_as_uint(f);
    u += 0x7FFFu + ((u >> 16) & 1u);   // round-to-nearest-even
    return (ushortT)(u >> 16);
}
__device__ __forceinline__ float bf2f(ushortT b) {
    return __uint_as_float(((unsigned)b) << 16);
}
// async global->LDS, 16B per lane; LDS dest = wave-uniform base + lane*16
__device__ __forceinline__ void gload16(const void* g, void* l) {
    __builtin_amdgcn_global_load_lds(
        (const __attribute__((address_space(1))) unsigned*)g,
        (__attribute__((address_space(3))) unsigned*)l, 16, 0, 0);
}

enum { EPI_BIAS_F32 = 2, EPI_TRANS_BF16 = 3, EPI_PQ = 5 };

// T2 swizzle: row stride 128B = 8 slots of 16B; physical slot = logical ^ (row&7).
// Involution applied on BOTH the global source (staging) and the ds_read side;
// LDS dest of global_load_lds stays linear (rule #21). Returns ushort offset.
__device__ __forceinline__ int swz_off(int row, int slot) {
    return row * 64 + (((slot ^ (row & 7)) & 7) << 3);
}

// ---------------- 256x256 8-wave pipelined GEMM (T2+T3+T4+T5) ----------------
// C = epi(A @ Bt^T [+bias]); A [M,K] bf16 (lda), Bt [N,K] bf16 (ldb). K%64==0.
// 512 thr = 8 waves (2M x 4N); BK=64; LDS 128 KiB double-buffered.
// Counted vmcnt(2) once per K-tile keeps next-tile loads in flight across
// barriers; raw s_barrier (no implicit vmcnt(0) drain). XOR slot swizzle kills
// the 16-way ds_read_b128 bank conflict of the linear layout (r6: 18.9M).
// Accumulation order per fragment identical to m97 -> bit-identical results.
template<int EPI, int NXT>
__global__ __launch_bounds__(512, 2)
void pipe_gemm(const ushortT* __restrict__ A, const ushortT* __restrict__ Bt,
               const float* __restrict__ bias, void* __restrict__ Cv,
               void* __restrict__ Cv2, int K, int lda, int ldb, int ldc, int cpx)
{
    // [A0 | A1 | B0 | B1], each 256*64 bf16 = 32 KiB
    __shared__ ushortT smem[4 * 16384];
    const int tid  = threadIdx.x;            // 0..511
    const int lane = tid & 63;
    const int w    = tid >> 6;               // 0..7
    const int wr   = w >> 2;                 // 0..1 : M half (128 rows)
    const int wc   = w & 3;                  // 0..3 : N quarter (64 cols)
    const int flat = blockIdx.x + blockIdx.y * NXT;
    const int swz  = (flat & 7) * cpx + (flat >> 3);   // XCD swizzle (nwg%8==0)
    const int n0   = (swz & (NXT - 1)) * 256;
    const int m0   = (swz / NXT) * 256;

    // staging map: issue q covers tile rows [q*64, q*64+64); thread -> row tid/8.
    // Global col is PRE-SWIZZLED: LDS physical slot (lane&7) of row srow receives
    // logical slot (lane&7)^(srow&7).  LDS dest stays linear (base + lane*16).
    const int srow  = tid >> 3;
    const int sscol = (((tid & 7) ^ (srow & 7)) & 7) << 3;   // elements

#define STG_A(buf, q, k0) gload16(A  + (size_t)(m0 + (q)*64 + srow) * lda + (k0) + sscol, \
                                  (char*)smem + (buf)*32768 + (q)*8192 + w*1024)
#define STG_B(buf, q, k0) gload16(Bt + (size_t)(n0 + (q)*64 + srow) * ldb + (k0) + sscol, \
                                  (char*)smem + 65536 + (buf)*32768 + (q)*8192 + w*1024)
#define BAR() asm volatile("s_barrier" ::: "memory")

    f32x4 acc[8][4];
    #pragma unroll
    for (int i = 0; i < 8; i++)
        #pragma unroll
        for (int j = 0; j < 4; j++) acc[i][j] = (f32x4){0.f, 0.f, 0.f, 0.f};

    const int NT = K >> 6;                   // K-tiles of 64

    // prologue: stage tile 0 into buf 0 (8 loads/wave)
    #pragma unroll
    for (int q = 0; q < 4; q++) { STG_A(0, q, 0); STG_B(0, q, 0); }

    const int mi = lane & 15;
    const int g4 = lane >> 4;                // 0..3 : k-slot sub-index

    for (int t = 0; t < NT; ++t) {
        const int c  = t & 1;
        const int nb = c ^ 1;
        const int kn = (t + 1) << 6;
        const bool hn = (t + 1 < NT);

        // ---- phase 0: stage 2, counted wait, sync, B frags + A quad 0 ----
        if (hn) {
            STG_A(nb, 0, kn); STG_A(nb, 1, kn);
            asm volatile("s_waitcnt vmcnt(2)" ::: "memory");  // tile t fully landed
        } else {
            asm volatile("s_waitcnt vmcnt(0)" ::: "memory");
        }
        BAR();

        short8 bf[4][2];
        #pragma unroll
        for (int nf = 0; nf < 4; nf++)
            #pragma unroll
            for (int ks = 0; ks < 2; ks++)
                bf[nf][ks] = *(const short8*)&smem[32768 + c * 16384 +
                                swz_off(wc * 64 + nf * 16 + mi, ks * 4 + g4)];

        #pragma unroll
        for (int p = 0; p < 4; p++) {
            if (p > 0) {
                if (hn) {
                    if (p == 1) { STG_A(nb, 2, kn); STG_A(nb, 3, kn); }
                    if (p == 2) { STG_B(nb, 0, kn); STG_B(nb, 1, kn); }
                    if (p == 3) { STG_B(nb, 2, kn); STG_B(nb, 3, kn); }
                }
                BAR();
            }
            short8 af[2][2];
            #pragma unroll
            for (int ii = 0; ii < 2; ii++)
                #pragma unroll
                for (int ks = 0; ks < 2; ks++)
                    af[ii][ks] = *(const short8*)&smem[c * 16384 +
                                    swz_off(wr * 128 + (p * 2 + ii) * 16 + mi, ks * 4 + g4)];
            __builtin_amdgcn_s_setprio(1);
            #pragma unroll
            for (int ks = 0; ks < 2; ks++)
                #pragma unroll
                for (int ii = 0; ii < 2; ii++)
                    #pragma unroll
                    for (int nf = 0; nf < 4; nf++)
                        acc[p * 2 + ii][nf] = __builtin_amdgcn_mfma_f32_16x16x32_bf16(
                            af[ii][ks], bf[nf][ks], acc[p * 2 + ii][nf], 0, 0, 0);
            __builtin_amdgcn_s_setprio(0);
        }
        BAR();   // all reads of buf c done before next iter's stage overwrites it
    }

    const int cr = (lane >> 4) * 4;
    #pragma unroll
    for (int i = 0; i < 8; i++) {
        #pragma unroll
        for (int j = 0; j < 4; j++) {
            const int gr = m0 + wr * 128 + i * 16 + cr;
            const int gc = n0 + wc * 64 + j * 16 + mi;
            #pragma unroll
            for (int r = 0; r < 4; r++) {
                float v = acc[i][j][r];
                if constexpr (EPI == EPI_BIAS_F32) {
                    ((float*)Cv)[(size_t)(gr + r) * ldc + gc] = v + bias[gc];
                } else {   // EPI_PQ: cols <1024 -> P (f32+bias), else -> Q (bf16)
                    if (gc < 1024)
                        ((float*)Cv)[(size_t)(gr + r) * ldc + gc] = v + bias[gc];
                    else
                        ((ushortT*)Cv2)[(size_t)(gr + r) * ldc + (gc - 1024)] = f2bf(v);
                }
            }
        }
    }
#undef STG_A
#undef STG_B
#undef BAR
}

// ---------------- bf16 MFMA GEMM (m97 structure, XCD-swizzled) ----------------
// Retained for the small Wc_t transpose GEMM.
template<int EPI, int NXT>
__global__ __launch_bounds__(256)
void mfma_gemm(const ushortT* __restrict__ A, const ushortT* __restrict__ Bt,
               const float* __restrict__ bias, void* __restrict__ Cv,
               void* __restrict__ Cv2, int K, int lda, int ldb, int ldc, int cpx)
{
    __shared__ ushortT As[128 * 32];
    __shared__ ushortT Bs[128 * 32];
    const int tid  = threadIdx.x;
    const int lane = tid & 63;
    const int w    = tid >> 6;
    const int wr   = (w >> 1) * 64;
    const int wc   = (w & 1) * 64;
    const int flat = blockIdx.x + blockIdx.y * NXT;
    const int swz  = (flat & 7) * cpx + (flat >> 3);
    const int n0   = (swz & (NXT - 1)) * 128;
    const int m0   = (swz / NXT) * 128;

    const int lrow = lane >> 2;
    const int lk   = (lane & 3) * 8;

    f32x4 acc[4][4];
    #pragma unroll
    for (int i = 0; i < 4; i++)
        #pragma unroll
        for (int j = 0; j < 4; j++) acc[i][j] = (f32x4){0.f, 0.f, 0.f, 0.f};

    for (int kk = 0; kk < K; kk += 32) {
        #pragma unroll
        for (int i = 0; i < 2; i++) {
            const ushortT* ga = A + (size_t)(m0 + w * 32 + i * 16 + lrow) * lda + kk + lk;
            gload16(ga, &As[(w * 32 + i * 16) * 32]);
            const ushortT* gb = Bt + (size_t)(n0 + w * 32 + i * 16 + lrow) * ldb + kk + lk;
            gload16(gb, &Bs[(w * 32 + i * 16) * 32]);
        }
        __syncthreads();

        const int mi = lane & 15;
        const int ko = (lane >> 4) * 8;
        short8 a[4], b[4];
        #pragma unroll
        for (int i = 0; i < 4; i++)
            a[i] = *(const short8*)&As[(wr + i * 16 + mi) * 32 + ko];
        #pragma unroll
        for (int j = 0; j < 4; j++)
            b[j] = *(const short8*)&Bs[(wc + j * 16 + mi) * 32 + ko];
        #pragma unroll
        for (int i = 0; i < 4; i++)
            #pragma unroll
            for (int j = 0; j < 4; j++)
                acc[i][j] = __builtin_amdgcn_mfma_f32_16x16x32_bf16(a[i], b[j], acc[i][j], 0, 0, 0);
        __syncthreads();
    }

    const int cr = (lane >> 4) * 4;
    const int cc = lane & 15;
    #pragma unroll
    for (int i = 0; i < 4; i++) {
        #pragma unroll
        for (int j = 0; j < 4; j++) {
            const int gr = m0 + wr + i * 16 + cr;
            const int gc = n0 + wc + j * 16 + cc;
            #pragma unroll
            for (int r = 0; r < 4; r++) {
                float v = acc[i][j][r];
                if constexpr (EPI == EPI_BIAS_F32)
                    ((float*)Cv)[(size_t)(gr + r) * ldc + gc] = v + bias[gc];
                else
                    ((ushortT*)Cv)[(size_t)gc * ldc + (gr + r)] = f2bf(v);
            }
        }
    }
}

// ---------------- row-granular gather + gelu:  G[m] = bf16(gelu(P[m] + Q[gidx[m]])) ----
__global__ __launch_bounds__(256)
void gelu_gather_k(const float* __restrict__ P, const ushortT* __restrict__ Q,
                   const int* __restrict__ gidx, ushortT* __restrict__ G)
{
    const int m = blockIdx.x;
    int t = gidx[m];                             // wave-uniform per block
    t = max(0, min(t, MTOT - 1));                // defensive clamp (poison-proof)
    const int c = threadIdx.x * 4;
    float4 p = *(const float4*)(P + (size_t)m * DMODEL + c);
    ushort4 q = *(const ushort4*)(Q + (size_t)t * DMODEL + c);
    ushortT o[4];
    o[0] = f2bf(gelu_f(p.x + bf2f(q.x)));
    o[1] = f2bf(gelu_f(p.y + bf2f(q.y)));
    o[2] = f2bf(gelu_f(p.z + bf2f(q.z)));
    o[3] = f2bf(gelu_f(p.w + bf2f(q.w)));
    *(ulong1*)(G + (size_t)m * DMODEL + c) = *(ulong1*)o;
}

// ---------------- fp32-grade split-bf16 GEMM, transposed bf16 out ----------
// Combined launch: grid (8,16); blockIdx.y>=8 selects the Wb half (K-offset +1024).
__global__ __launch_bounds__(256)
void wsplit_gemm(const ushortT* __restrict__ Ah, const ushortT* __restrict__ Al,
                 const ushortT* __restrict__ Bh0, const ushortT* __restrict__ Bl0,
                 ushortT* __restrict__ Ct0, int K, int lda, int ldb, int ldc)
{
    __shared__ ushortT Ash[128 * 32], Asl[128 * 32];
    __shared__ ushortT Bsh[128 * 32], Bsl[128 * 32];
    const int tid  = threadIdx.x;
    const int lane = tid & 63;
    const int w    = tid >> 6;
    const int wr   = (w >> 1) * 64;
    const int wc   = (w & 1) * 64;
    const int sel  = blockIdx.y >> 3;
    const int m0   = (blockIdx.y & 7) * 128;
    const int n0   = blockIdx.x * 128;
    const ushortT* Bh = Bh0 + sel * 1024;        // K-offset into Wrt1t (ldb = 2048)
    const ushortT* Bl = Bl0 + sel * 1024;
    ushortT* Ct = Ct0 + (size_t)sel * 1024 * 1024;
    const int lrow = lane >> 2;
    const int lk   = (lane & 3) * 8;

    f32x4 acc[4][4];
    #pragma unroll
    for (int i = 0; i < 4; i++)
        #pragma unroll
        for (int j = 0; j < 4; j++) acc[i][j] = (f32x4){0.f, 0.f, 0.f, 0.f};

    for (int kk = 0; kk < K; kk += 32) {
        #pragma unroll
        for (int i = 0; i < 2; i++) {
            const size_t aoff = (size_t)(m0 + w * 32 + i * 16 + lrow) * lda + kk + lk;
            const size_t boff = (size_t)(n0 + w * 32 + i * 16 + lrow) * ldb + kk + lk;
            const int ldst = (w * 32 + i * 16) * 32;
            gload16(Ah + aoff, &Ash[ldst]);
            gload16(Al + aoff, &Asl[ldst]);
            gload16(Bh + boff, &Bsh[ldst]);
            gload16(Bl + boff, &Bsl[ldst]);
        }
        __syncthreads();

        const int mi = lane & 15;
        const int ko = (lane >> 4) * 8;
        short8 ah[4], al[4], bh[4], bl[4];
        #pragma unroll
        for (int i = 0; i < 4; i++) {
            ah[i] = *(const short8*)&Ash[(wr + i * 16 + mi) * 32 + ko];
            al[i] = *(const short8*)&Asl[(wr + i * 16 + mi) * 32 + ko];
        }
        #pragma unroll
        for (int j = 0; j < 4; j++) {
            bh[j] = *(const short8*)&Bsh[(wc + j * 16 + mi) * 32 + ko];
            bl[j] = *(const short8*)&Bsl[(wc + j * 16 + mi) * 32 + ko];
        }
        #pragma unroll
        for (int i = 0; i < 4; i++)
            #pragma unroll
            for (int j = 0; j < 4; j++) {
                acc[i][j] = __builtin_amdgcn_mfma_f32_16x16x32_bf16(ah[i], bh[j], acc[i][j], 0, 0, 0);
                acc[i][j] = __builtin_amdgcn_mfma_f32_16x16x32_bf16(ah[i], bl[j], acc[i][j], 0, 0, 0);
                acc[i][j] = __builtin_amdgcn_mfma_f32_16x16x32_bf16(al[i], bh[j], acc[i][j], 0, 0, 0);
            }
        __syncthreads();
    }

    const int cr = (lane >> 4) * 4;
    const int cc = lane & 15;
    #pragma unroll
    for (int i = 0; i < 4; i++)
        #pragma unroll
        for (int j = 0; j < 4; j++) {
            const int gr = m0 + wr + i * 16 + cr;
            const int gc = n0 + wc + j * 16 + cc;
            #pragma unroll
            for (int r = 0; r < 4; r++)
                Ct[(size_t)gc * ldc + (gr + r)] = f2bf(acc[i][j][r]);
        }
}

// ---------------- encoder fast path: split-bf16 MFMA (fp32-grade precision) ----
// grid (4,128), XCD-swizzled.
__global__ __launch_bounds__(256)
void enc_gemm(const ushortT* __restrict__ Ah, const ushortT* __restrict__ Al,
              const ushortT* __restrict__ Bh, const ushortT* __restrict__ Bl,
              const float* __restrict__ bias, float* __restrict__ C)
{
    __shared__ ushortT Ash[128 * 32], Asl[128 * 32];
    __shared__ ushortT Bsh[128 * 32], Bsl[128 * 32];
    const int tid  = threadIdx.x;
    const int lane = tid & 63;
    const int w    = tid >> 6;
    const int wr   = (w >> 1) * 64;
    const int wc   = (w & 1) * 64;
    const int flat = blockIdx.x + (blockIdx.y << 2);       // nwg = 512
    const int swz  = (flat & 7) * 64 + (flat >> 3);
    const int n0   = (swz & 3) * 128;
    const int m0   = (swz >> 2) * 128;
    const int lrow = lane >> 2;
    const int lk   = (lane & 3) * 8;

    f32x4 acc[4][4];
    #pragma unroll
    for (int i = 0; i < 4; i++)
        #pragma unroll
        for (int j = 0; j < 4; j++) acc[i][j] = (f32x4){0.f, 0.f, 0.f, 0.f};

    for (int kk = 0; kk < DMODEL; kk += 32) {
        #pragma unroll
        for (int i = 0; i < 2; i++) {
            const size_t aoff = (size_t)(m0 + w * 32 + i * 16 + lrow) * DMODEL + kk + lk;
            const size_t boff = (size_t)(n0 + w * 32 + i * 16 + lrow) * DMODEL + kk + lk;
            const int ldst = (w * 32 + i * 16) * 32;
            gload16(Ah + aoff, &Ash[ldst]);
            gload16(Al + aoff, &Asl[ldst]);
            gload16(Bh + boff, &Bsh[ldst]);
            gload16(Bl + boff, &Bsl[ldst]);
        }
        __syncthreads();

        const int mi = lane & 15;
        const int ko = (lane >> 4) * 8;
        short8 ah[4], al[4], bh[4], bl[4];
        #pragma unroll
        for (int i = 0; i < 4; i++) {
            ah[i] = *(const short8*)&Ash[(wr + i * 16 + mi) * 32 + ko];
            al[i] = *(const short8*)&Asl[(wr + i * 16 + mi) * 32 + ko];
        }
        #pragma unroll
        for (int j = 0; j < 4; j++) {
            bh[j] = *(const short8*)&Bsh[(wc + j * 16 + mi) * 32 + ko];
            bl[j] = *(const short8*)&Bsl[(wc + j * 16 + mi) * 32 + ko];
        }
        #pragma unroll
        for (int i = 0; i < 4; i++)
            #pragma unroll
            for (int j = 0; j < 4; j++) {
                acc[i][j] = __builtin_amdgcn_mfma_f32_16x16x32_bf16(ah[i], bh[j], acc[i][j], 0, 0, 0);
                acc[i][j] = __builtin_amdgcn_mfma_f32_16x16x32_bf16(ah[i], bl[j], acc[i][j], 0, 0, 0);
                acc[i][j] = __builtin_amdgcn_mfma_f32_16x16x32_bf16(al[i], bh[j], acc[i][j], 0, 0, 0);
            }
        __syncthreads();
    }

    const int cr = (lane >> 4) * 4;
    const int cc = lane & 15;
    #pragma unroll
    for (int i = 0; i < 4; i++)
        #pragma unroll
        for (int j = 0; j < 4; j++) {
            const int gr = m0 + wr + i * 16 + cr;
            const int gc = n0 + wc + j * 16 + cc;
            #pragma unroll
            for (int r = 0; r < 4; r++)
                C[(size_t)(gr + r) * 512 + gc] = gelu_f(acc[i][j][r] + bias[gc]);
        }
}

// logit = gelu_row . W_re2 (fp64 accum of f32 values); flag borderline tokens
__global__ __launch_bounds__(256)
void target2_k(const float* __restrict__ Genc, const float* __restrict__ W2,
               const float* __restrict__ b2, float* __restrict__ outT,
               float* __restrict__ outS, int* __restrict__ gidx,
               int* __restrict__ cnt, int* __restrict__ list)
{
    const int m = blockIdx.x * 4 + (threadIdx.x >> 6);
    const int lane = threadIdx.x & 63;
    const float* gr = Genc + (size_t)m * 512;
    double s = 0.0;
    #pragma unroll 4
    for (int j = lane; j < 512; j += 64) s = fma((double)gr[j], (double)W2[j], s);
    #pragma unroll
    for (int off = 32; off; off >>= 1) s += __shfl_down(s, off);
    if (lane == 0) {
        double logit = s + (double)b2[0];
        double str = 1.0 / (1.0 + exp(-logit));
        double r = str * (double)(NSEQ - 1);
        double n = rint(r);
        double dist = fabs(r - n);             // distance to nearest integer
        n = fmin(fmax(n, 0.0), (double)(NSEQ - 1));
        int t = (int)n;
        outT[m] = (float)t;
        outS[m] = (float)str;
        gidx[m] = ((m >> 12) << 12) + t;
        if (dist > 0.46) {                      // within 0.04 of a .5 boundary
            int ix = atomicAdd(cnt, 1) & (MTOT - 1);   // defensive mask (list is 64KB)
            list[ix] = m;
        }
    }
}

// exact fp64 recompute for flagged tokens.
// v3: 1024 thr = 4 k-groups x 256 j-threads; k-loop 256 iters (was 1024 serial).
// Cuts the per-block latency critical path ~4x (r7: fixup was the top dispatch
// at 100us, latency-bound at 1 wave/SIMD with a 1024-iter serial fp64 loop).
// fp64 partials combined in LDS; summation-order change only (~1e-15).
#define FIX_T 4
__global__ __launch_bounds__(1024)
void fixup_k(const float* __restrict__ h, const float* __restrict__ W1,
             const float* __restrict__ b1, const float* __restrict__ W2,
             const float* __restrict__ b2, const int* __restrict__ cnt_p,
             const int* __restrict__ list, float* __restrict__ outT,
             float* __restrict__ outS, int* __restrict__ gidx)
{
    __shared__ float  hrow[FIX_T][1024];
    __shared__ double part[FIX_T][4][512];
    __shared__ double red[FIX_T][8];
    const int tid = threadIdx.x;      // 0..1023
    const int kg  = tid >> 8;         // k-group 0..3
    const int jj  = tid & 255;        // owns columns jj and jj+256
    const int cnt = min(*cnt_p, MTOT);           // defensive clamp
    for (int base = (int)blockIdx.x * FIX_T; base < cnt;
         base += (int)gridDim.x * FIX_T) {
        const int nt = min(FIX_T, cnt - base);
        for (int t = 0; t < nt; t++) {
            const int m = list[base + t];
            hrow[t][tid] = h[(size_t)m * 1024 + tid];   // coalesced, 1 float/thread
        }
        __syncthreads();

        double a0[FIX_T], a1[FIX_T];
        #pragma unroll
        for (int t = 0; t < FIX_T; t++) { a0[t] = 0.0; a1[t] = 0.0; }
        const int kbase = kg * 256;
        #pragma unroll 4
        for (int kk = 0; kk < 256; kk++) {
            const int k = kbase + kk;
            const double wa = (double)W1[(size_t)k * 512 + jj];
            const double wb = (double)W1[(size_t)k * 512 + jj + 256];
            #pragma unroll
            for (int t = 0; t < FIX_T; t++) {
                const double hv = (double)hrow[t][k];
                a0[t] = fma(hv, wa, a0[t]);
                a1[t] = fma(hv, wb, a1[t]);
            }
        }
        #pragma unroll
        for (int t = 0; t < FIX_T; t++) {
            part[t][kg][jj]       = a0[t];
            part[t][kg][jj + 256] = a1[t];
        }
        __syncthreads();

        // waves 0..7 (tid<512): combine k-group partials, gelu_d, dot W2, reduce
        if (tid < 512) {
            const int col  = tid;
            const int lane = tid & 63;
            const int wv   = tid >> 6;        // 0..7
            const double b1c = (double)b1[col];
            const double w2c = (double)W2[col];
            #pragma unroll
            for (int t = 0; t < FIX_T; t++) {
                double hid = part[t][0][col] + part[t][1][col]
                           + part[t][2][col] + part[t][3][col] + b1c;
                double v = gelu_d(hid) * w2c;
                #pragma unroll
                for (int off = 32; off; off >>= 1) v += __shfl_down(v, off);
                if (lane == 0) red[t][wv] = v;
            }
        }
        __syncthreads();
        if (tid < nt) {
            const int t = tid;
            double logit = (double)b2[0];
            #pragma unroll
            for (int q = 0; q < 8; q++) logit += red[t][q];
            double str = 1.0 / (1.0 + exp(-logit));
            double r = str * (double)(NSEQ - 1);
            double n = rint(r);
            n = fmin(fmax(n, 0.0), (double)(NSEQ - 1));
            const int m = list[base + t];
            const int ti = (int)n;
            outT[m] = (float)ti;
            outS[m] = (float)str;
            gidx[m] = ((m >> 12) << 12) + ti;
        }
        __syncthreads();
    }
}

__global__ __launch_bounds__(256)
void biascomb_k(const float* __restrict__ brt2, const float* __restrict__ Wo,
                float* __restrict__ bc)
{
    int j = blockIdx.x * 256 + threadIdx.x;
    float s = 0.f;
    for (int e = 0; e < DMODEL; e++) s = fmaf(brt2[e], Wo[e * DMODEL + j], s);
    bc[j] = s;
}

// f32 -> bf16 straight cast
__global__ __launch_bounds__(256)
void cast_k(const float* __restrict__ x, ushortT* __restrict__ y, int n)
{
    int i = (blockIdx.x * 256 + threadIdx.x) * 4;
    if (i < n) {
        float4 v = *(const float4*)(x + i);
        ushortT o[4] = { f2bf(v.x), f2bf(v.y), f2bf(v.z), f2bf(v.w) };
        *(ulong1*)&y[i] = *(ulong1*)o;
    }
}

// f32 -> (hi bf16, lo bf16) 2-way split
__global__ __launch_bounds__(256)
void split_cast_k(const float* __restrict__ x, ushortT* __restrict__ yh,
                  ushortT* __restrict__ yl, int n)
{
    int i = (blockIdx.x * 256 + threadIdx.x) * 4;
    if (i < n) {
        float4 v = *(const float4*)(x + i);
        float vv[4] = { v.x, v.y, v.z, v.w };
        ushortT oh[4], ol[4];
        #pragma unroll
        for (int q = 0; q < 4; q++) {
            oh[q] = f2bf(vv[q]);
            ol[q] = f2bf(vv[q] - bf2f(oh[q]));
        }
        *(ulong1*)&yh[i] = *(ulong1*)oh;
        *(ulong1*)&yl[i] = *(ulong1*)ol;
    }
}

// W [K][N] f32 -> Wt [N][K] bf16
__global__ __launch_bounds__(256)
void transcast_k(const float* __restrict__ W, ushortT* __restrict__ Wt, int K, int N)
{
    __shared__ float t[32][33];
    const int tx = threadIdx.x & 31, ty = threadIdx.x >> 5;
    const int n0 = blockIdx.x * 32, k0 = blockIdx.y * 32;
    #pragma unroll
    for (int r = 0; r < 32; r += 8)
        t[ty + r][tx] = W[(size_t)(k0 + ty + r) * N + n0 + tx];
    __syncthreads();
    #pragma unroll
    for (int r = 0; r < 32; r += 8)
        Wt[(size_t)(n0 + ty + r) * K + k0 + tx] = f2bf(t[tx][ty + r]);
}

// W [K][N] f32 -> Wt_hi/lo [N][K] bf16 split
__global__ __launch_bounds__(256)
void split_transcast_k(const float* __restrict__ W, ushortT* __restrict__ Wth,
                       ushortT* __restrict__ Wtl, int K, int N)
{
    __shared__ float t[32][33];
    const int tx = threadIdx.x & 31, ty = threadIdx.x >> 5;
    const int n0 = blockIdx.x * 32, k0 = blockIdx.y * 32;
    #pragma unroll
    for (int r = 0; r < 32; r += 8)
        t[ty + r][tx] = W[(size_t)(k0 + ty + r) * N + n0 + tx];
    __syncthreads();
    #pragma unroll
    for (int r = 0; r < 32; r += 8) {
        float x = t[tx][ty + r];
        ushortT hi = f2bf(x);
        Wth[(size_t)(n0 + ty + r) * K + k0 + tx] = hi;
        Wtl[(size_t)(n0 + ty + r) * K + k0 + tx] = f2bf(x - bf2f(hi));
    }
}

extern "C" void kernel_launch(void* const* d_in, const int* in_sizes, int n_in,
                              void* d_out, int out_size, void* d_ws, size_t ws_size,
                              hipStream_t stream)
{
    const float* h     = (const float*)d_in[0];
    const float* W_re1 = (const float*)d_in[1];
    const float* b_re1 = (const float*)d_in[2];
    const float* W_re2 = (const float*)d_in[3];
    const float* b_re2 = (const float*)d_in[4];
    const float* W_v   = (const float*)d_in[5];
    const float* W_rt1 = (const float*)d_in[6];
    const float* b_rt1 = (const float*)d_in[7];
    const float* W_rt2 = (const float*)d_in[8];
    const float* b_rt2 = (const float*)d_in[9];
    const float* W_o   = (const float*)d_in[10];

    float* z    = (float*)d_out;                        // [16384,1024] f32
    float* outT = z + (size_t)MTOT * DMODEL;
    float* outS = outT + MTOT;
    ushortT* Q    = (ushortT*)z;                        // bf16 [16384,1024], lower 32 MB of z region
    ushortT* h_hi = (ushortT*)z + (size_t)MTOT * DMODEL;// bf16, upper 32 MB of z region

    char* ws = (char*)d_ws;
    ushortT* G       = (ushortT*)ws;                          // 32 MB  gelu(pre) bf16
    float*   Genc    = (float*)(ws + (32ull  << 20));         // 32 MB  encoder gelu f32 (freed after target2)
    ushortT* h_lo    = (ushortT*)(ws + (64ull  << 20));       // 32 MB  (freed after enc_gemm)
    float*   P       = (float*)(ws + (32ull  << 20));         // 64 MB  pre-act f32, REUSES Genc+h_lo region
    ushortT* Wrt1t_h = (ushortT*)(ws + (96ull  << 20));       // 4 MB  [1024][2048]
    ushortT* Wrt1t_l = (ushortT*)(ws + (100ull << 20));       // 4 MB
    ushortT* Wv_h    = (ushortT*)(ws + (104ull << 20));       // 2 MB  [1024][1024]
    ushortT* Wv_l    = (ushortT*)(ws + (106ull << 20));       // 2 MB
    ushortT* Wa_t    = (ushortT*)(ws + (108ull << 20));       // 4 MB  [Wa;Wb]^T bf16 [2048][1024]
    ushortT* Wo_t    = (ushortT*)(ws + (112ull << 20));       // 2 MB
    ushortT* Wrt2_b  = (ushortT*)(ws + (114ull << 20));       // 2 MB
    ushortT* Wc_t    = (ushortT*)(ws + (116ull << 20));       // 2 MB
    ushortT* Wre1t_h = (ushortT*)(ws + (118ull << 20));       // 1 MB [512][1024]
    ushortT* Wre1t_l = (ushortT*)(ws + (119ull << 20));       // 1 MB
    float*   b_c     = (float*)(ws + (120ull << 20));         // 4 KB
    int*     cnt     = (int*)  (ws + (120ull << 20) + 4096);  // 4 KB
    int*     gidx    = (int*)  (ws + (120ull << 20) + 8192);  // 64 KB
    int*     list    = (int*)  (ws + (120ull << 20) + 8192 + 65536); // 64 KB

    // --- casts / splits / transposes ---
    split_cast_k<<<dim3(MTOT * DMODEL / 1024), 256, 0, stream>>>(h, h_hi, h_lo, MTOT * DMODEL);
    split_cast_k<<<dim3(DMODEL * DMODEL / 1024), 256, 0, stream>>>(W_v, Wv_h, Wv_l, DMODEL * DMODEL);
    split_transcast_k<<<dim3(16, 32), 256, 0, stream>>>(W_re1, Wre1t_h, Wre1t_l, DMODEL, 512);
    split_transcast_k<<<dim3(32, 64), 256, 0, stream>>>(W_rt1, Wrt1t_h, Wrt1t_l, 2 * DMODEL, DMODEL);
    cast_k<<<dim3(DMODEL * DMODEL / 1024), 256, 0, stream>>>(W_rt2, Wrt2_b, DMODEL * DMODEL);
    transcast_k<<<dim3(32, 32), 256, 0, stream>>>(W_o, Wo_t, DMODEL, DMODEL);
    biascomb_k<<<dim3(4), 256, 0, stream>>>(b_rt2, W_o, b_c);

    // --- combined weights [Wa;Wb]^T in ONE launch (fp32-grade; 128 blocks) ---
    wsplit_gemm<<<dim3(8, 16), 256, 0, stream>>>(Wv_h, Wv_l, Wrt1t_h, Wrt1t_l,
                                                 Wa_t, DMODEL, DMODEL, 2 * DMODEL, DMODEL);

    // --- encoder fast path (split-bf16 MFMA, fp32-grade) ---
    enc_gemm<<<dim3(4, 128), 256, 0, stream>>>(h_hi, h_lo, Wre1t_h, Wre1t_l, b_re1, Genc);

    hipMemsetAsync(cnt, 0, 4, stream);
    target2_k<<<dim3(MTOT / 4), 256, 0, stream>>>(Genc, W_re2, b_re2, outT, outS, gidx, cnt, list);
    // exact fp64 recompute of borderline tokens (~8%), k-split latency-optimized
    fixup_k<<<dim3(1024), 1024, 0, stream>>>(h, W_re1, b_re1, W_re2, b_re2, cnt, list,
                                             outT, outS, gidx);

    // --- z path ---
    mfma_gemm<EPI_TRANS_BF16, 8><<<dim3(8, 8), 256, 0, stream>>>(
        Wrt2_b, Wo_t, nullptr, (void*)Wc_t, nullptr, DMODEL, DMODEL, DMODEL, DMODEL, 8);

    // [P|Q] = h @ [Wa;Wb]^T  — 256² 8-wave pipelined GEMM (counted vmcnt + T2 swizzle)
    pipe_gemm<EPI_PQ, 8><<<dim3(8, 64), 512, 0, stream>>>(
        h_hi, Wa_t, b_rt1, (void*)P, (void*)Q, DMODEL, DMODEL, DMODEL, DMODEL, 64);

    // G = bf16(gelu(P + Q[gidx]))  — row-granular coalesced gather
    gelu_gather_k<<<dim3(MTOT), 256, 0, stream>>>(P, Q, gidx, G);

    // z = G @ Wc + b_c  — pipelined GEMM
    pipe_gemm<EPI_BIAS_F32, 4><<<dim3(4, 64), 512, 0, stream>>>(
        G, Wc_t, b_c, (void*)z, nullptr, DMODEL, DMODEL, DMODEL, DMODEL, 32);
}